// Round 7
// baseline (708.750 us; speedup 1.0000x reference)
//
#include <hip/hip_runtime.h>
#include <hip/hip_bf16.h>
#include <cstdint>
#include <cstddef>

// Problem constants (from reference)
#define D_MODEL 1024
#define D_INNER 2048
#define NSTATE  16
#define DTRANK  64
#define BATCH   2
#define SEQLEN  2048
#define BL      (BATCH*SEQLEN)   // 4096 tokens
#define NSEG    32
#define TSEG    (SEQLEN/NSEG)    // 64
#define SKX     8                // split-K factor for x_proj
#define KCH     (D_INNER/SKX)    // 256
#define LOG2E   1.4426950408889634f

typedef __attribute__((ext_vector_type(8))) short s16x8;
typedef __attribute__((ext_vector_type(4))) float f32x4;

__device__ __forceinline__ float softplusf(float x) {
    return fmaxf(x, 0.f) + log1pf(expf(-fabsf(x)));
}
__device__ __forceinline__ unsigned short f2bf(float x) {
    __hip_bfloat16 b = __float2bfloat16(x);
    return *(unsigned short*)&b;
}
__device__ __forceinline__ float bf2f(unsigned short u) {
    __hip_bfloat16 b; *(unsigned short*)&b = u;
    return __bfloat162float(b);
}
// async global->LDS, 16B per lane (dest must be linear: base + lane*16)
__device__ __forceinline__ void gll16(const void* g, void* l) {
    __builtin_amdgcn_global_load_lds(
        (const __attribute__((address_space(1))) void*)g,
        (__attribute__((address_space(3))) void*)l, 16, 0, 0);
}

// ---- lbp[n,r] = lora_B[n,r] * mask[n] * 2.0 ----
__global__ __launch_bounds__(256) void premul_kernel(
        const float* __restrict__ lb, const float* __restrict__ mask,
        float* __restrict__ out, int total) {
    int i = blockIdx.x * 256 + threadIdx.x;
    if (i < total) out[i] = lb[i] * mask[i >> 4] * 2.0f;
}

// ---- T[m,r] = sum_k X[m,k] * LA[r,k]   (r < 16) ----
__global__ __launch_bounds__(256) void lora_t_kernel(
        const float* __restrict__ X, int ldx,
        const float* __restrict__ LA, int K,
        float* __restrict__ T) {
    int m = blockIdx.x;
    int r = threadIdx.x >> 4;
    int l = threadIdx.x & 15;
    const float* xrow = X + (size_t)m * ldx;
    const float* arow = LA + (size_t)r * K;
    float s = 0.f;
    for (int k = 4 * l; k < K; k += 64) {
        float4 xv = *(const float4*)(xrow + k);
        float4 av = *(const float4*)(arow + k);
        s += xv.x * av.x + xv.y * av.y + xv.z * av.z + xv.w * av.w;
    }
    #pragma unroll
    for (int o = 8; o; o >>= 1) s += __shfl_xor(s, o, 16);
    if (l == 0) T[(size_t)m * 16 + r] = s;
}

// ---- hi/lo bf16 split: hi=bf16(v), lo=bf16(v-hi) ----
__global__ __launch_bounds__(256) void hilo_kernel(
        const float* __restrict__ src, int lda, int K4, int KP,
        unsigned short* __restrict__ hi, unsigned short* __restrict__ lo,
        int total4) {
    int idx = blockIdx.x * 256 + threadIdx.x;
    if (idx >= total4) return;
    int m = idx / K4;
    int kq = idx - m * K4;
    float4 v = *(const float4*)(src + (size_t)m * lda + kq * 4);
    ushort4 h, l;
    h.x = f2bf(v.x); l.x = f2bf(v.x - bf2f(h.x));
    h.y = f2bf(v.y); l.y = f2bf(v.y - bf2f(h.y));
    h.z = f2bf(v.z); l.z = f2bf(v.z - bf2f(h.z));
    h.w = f2bf(v.w); l.w = f2bf(v.w - bf2f(h.w));
    *(ushort4*)(hi + (size_t)m * KP + kq * 4) = h;
    *(ushort4*)(lo + (size_t)m * KP + kq * 4) = l;
}

// ---- LoRA K-extension columns ----
__global__ __launch_bounds__(256) void ext_kernel(
        const float* __restrict__ t16, int K, int KP,
        unsigned short* __restrict__ hi, unsigned short* __restrict__ lo,
        int M) {
    int idx = blockIdx.x * 256 + threadIdx.x;
    if (idx >= M * 32) return;
    int c = idx & 31, m = idx >> 5;
    unsigned short hv = 0;
    if (c < 16) hv = f2bf(t16[(size_t)m * 16 + c]);
    hi[(size_t)m * KP + K + c] = hv;
    lo[(size_t)m * KP + K + c] = 0;
}

// ---- hi/lo bf16 MFMA GEMM, register-fragment pipelined 2-phase ----
// Per K-tile: {lgkm+vmcnt drain -> barrier} certifies (a) this wave's frag
// reads done, (b) ALL waves' next-tile DMA landed. Then: refill the freed
// buffer, issue next-tile ds_reads into the other register set, and run
// 48 MFMA on the current set — reads + stage flight hide under MFMA.
template<int EPI>
__global__ __launch_bounds__(256, 2) void mfma_gemm(
        const unsigned short* __restrict__ Ahg, const unsigned short* __restrict__ Alg,
        const unsigned short* __restrict__ Whg, const unsigned short* __restrict__ Wlg,
        int KP, float* __restrict__ C, int ldc,
        const float* __restrict__ bias) {
    __shared__ __align__(16) short Ash[2][4][128][8];
    __shared__ __align__(16) short Asl[2][4][128][8];
    __shared__ __align__(16) short Wsh[2][4][128][8];
    __shared__ __align__(16) short Wsl[2][4][128][8];
    const int tid = threadIdx.x;
    const int bn0 = blockIdx.x * 128, bm0 = blockIdx.y * 128;
    const int wave = tid >> 6, lane = tid & 63;
    const int wr = (wave >> 1) * 64, wc = (wave & 1) * 64;
    const int fr = lane & 15, fg = lane >> 4;
    const int KT = KP >> 5;
    const int srow = tid & 127, skg = tid >> 7;

    const unsigned short* pAh = Ahg + (size_t)(bm0 + srow) * KP + skg * 8;
    const unsigned short* pAl = Alg + (size_t)(bm0 + srow) * KP + skg * 8;
    const unsigned short* pWh = Whg + (size_t)(bn0 + srow) * KP + skg * 8;
    const unsigned short* pWl = Wlg + (size_t)(bn0 + srow) * KP + skg * 8;

    f32x4 acc[4][4];
    #pragma unroll
    for (int i = 0; i < 4; ++i)
        #pragma unroll
        for (int j = 0; j < 4; ++j) acc[i][j] = (f32x4){0.f, 0.f, 0.f, 0.f};

    auto stage = [&](int kt, int pb) {
        const int koff = kt * 32;
        gll16(pAh + koff,      &Ash[pb][skg    ][srow][0]);
        gll16(pAh + koff + 16, &Ash[pb][skg + 2][srow][0]);
        gll16(pAl + koff,      &Asl[pb][skg    ][srow][0]);
        gll16(pAl + koff + 16, &Asl[pb][skg + 2][srow][0]);
        gll16(pWh + koff,      &Wsh[pb][skg    ][srow][0]);
        gll16(pWh + koff + 16, &Wsh[pb][skg + 2][srow][0]);
        gll16(pWl + koff,      &Wsl[pb][skg    ][srow][0]);
        gll16(pWl + koff + 16, &Wsl[pb][skg + 2][srow][0]);
    };
    auto dsread = [&](s16x8 (&ah)[4], s16x8 (&al)[4],
                      s16x8 (&wh)[4], s16x8 (&wl)[4], int pb) {
        #pragma unroll
        for (int i = 0; i < 4; ++i) {
            ah[i] = *(const s16x8*)&Ash[pb][fg][wr + i * 16 + fr][0];
            al[i] = *(const s16x8*)&Asl[pb][fg][wr + i * 16 + fr][0];
            wh[i] = *(const s16x8*)&Wsh[pb][fg][wc + i * 16 + fr][0];
            wl[i] = *(const s16x8*)&Wsl[pb][fg][wc + i * 16 + fr][0];
        }
    };
    auto domfma = [&](s16x8 (&ah)[4], s16x8 (&al)[4],
                      s16x8 (&wh)[4], s16x8 (&wl)[4]) {
        __builtin_amdgcn_s_setprio(1);
        #pragma unroll
        for (int i = 0; i < 4; ++i)
            #pragma unroll
            for (int j = 0; j < 4; ++j) {
                acc[i][j] = __builtin_amdgcn_mfma_f32_16x16x32_bf16(ah[i], wh[j], acc[i][j], 0, 0, 0);
                acc[i][j] = __builtin_amdgcn_mfma_f32_16x16x32_bf16(ah[i], wl[j], acc[i][j], 0, 0, 0);
                acc[i][j] = __builtin_amdgcn_mfma_f32_16x16x32_bf16(al[i], wh[j], acc[i][j], 0, 0, 0);
            }
        __builtin_amdgcn_s_setprio(0);
    };

    s16x8 ah0[4], al0[4], wh0[4], wl0[4];
    s16x8 ah1[4], al1[4], wh1[4], wl1[4];

    // prologue: tile 0 into LDS, certify, frag-read it; issue tile 1
    stage(0, 0);
    asm volatile("s_waitcnt vmcnt(0)" ::: "memory");
    __builtin_amdgcn_sched_barrier(0);
    __builtin_amdgcn_s_barrier();
    __builtin_amdgcn_sched_barrier(0);
    dsread(ah0, al0, wh0, wl0, 0);
    if (KT > 1) stage(1, 1);

    int kt = 0;
    while (true) {
        // even kt: frags in set0 (from buf0); tile kt+1 -> buf1
        asm volatile("s_waitcnt vmcnt(0) lgkmcnt(0)" ::: "memory");
        __builtin_amdgcn_sched_barrier(0);
        __builtin_amdgcn_s_barrier();
        __builtin_amdgcn_sched_barrier(0);
        if (kt + 2 < KT) stage(kt + 2, 0);
        if (kt + 1 < KT) dsread(ah1, al1, wh1, wl1, 1);
        __builtin_amdgcn_sched_barrier(0);
        domfma(ah0, al0, wh0, wl0);
        if (++kt == KT) break;
        // odd kt: frags in set1 (from buf1); tile kt+1 -> buf0
        asm volatile("s_waitcnt vmcnt(0) lgkmcnt(0)" ::: "memory");
        __builtin_amdgcn_sched_barrier(0);
        __builtin_amdgcn_s_barrier();
        __builtin_amdgcn_sched_barrier(0);
        if (kt + 2 < KT) stage(kt + 2, 1);
        if (kt + 1 < KT) dsread(ah0, al0, wh0, wl0, 0);
        __builtin_amdgcn_sched_barrier(0);
        domfma(ah1, al1, wh1, wl1);
        if (++kt == KT) break;
    }
    // C/D layout: col = lane&15, row = (lane>>4)*4 + q
    #pragma unroll
    for (int i = 0; i < 4; ++i) {
        #pragma unroll
        for (int j = 0; j < 4; ++j) {
            int n = bn0 + wc + j * 16 + fr;
            #pragma unroll
            for (int q = 0; q < 4; ++q) {
                int m = bm0 + wr + i * 16 + fg * 4 + q;
                float v = acc[i][j][q];
                if (EPI == 2) v = softplusf(v + bias[n]);
                C[(size_t)m * ldc + n] = v;
            }
        }
    }
}

// ---- fp32 tiled GEMM (x_proj split-K; N=96) ----
__global__ __launch_bounds__(256) void gemm_f32_kernel(
        const float* __restrict__ A, int lda,
        const float* __restrict__ W, int ldw,
        float* __restrict__ C, int ldc,
        int M, int N, int K, int kchunk) {
    __shared__ float As[8][128];
    __shared__ float Bs[8][128];
    if (kchunk) {
        A += (size_t)blockIdx.z * kchunk;
        W += (size_t)blockIdx.z * kchunk;
        C += (size_t)blockIdx.z * M * ldc;
    }
    const int tid = threadIdx.x;
    const int tx = tid & 15, ty = tid >> 4;
    const int bn0 = blockIdx.x * 128, bm0 = blockIdx.y * 128;
    const int lrow = tid >> 1;
    const int lk   = (tid & 1) * 4;
    const int nk = K >> 3;

    float acc[8][8];
    #pragma unroll
    for (int i = 0; i < 8; ++i)
        #pragma unroll
        for (int j = 0; j < 8; ++j) acc[i][j] = 0.f;

    float4 av, wv;
    {
        av = *(const float4*)(A + (size_t)(bm0 + lrow) * lda + lk);
        int n = bn0 + lrow;
        wv = (n < N) ? *(const float4*)(W + (size_t)n * ldw + lk)
                     : make_float4(0.f, 0.f, 0.f, 0.f);
    }
    for (int kt = 0; kt < nk; ++kt) {
        __syncthreads();
        As[lk + 0][lrow] = av.x; As[lk + 1][lrow] = av.y;
        As[lk + 2][lrow] = av.z; As[lk + 3][lrow] = av.w;
        Bs[lk + 0][lrow] = wv.x; Bs[lk + 1][lrow] = wv.y;
        Bs[lk + 2][lrow] = wv.z; Bs[lk + 3][lrow] = wv.w;
        __syncthreads();
        int kt1 = kt + 1;
        if (kt1 < nk) {
            int n = bn0 + lrow;
            av = *(const float4*)(A + (size_t)(bm0 + lrow) * lda + (size_t)kt1 * 8 + lk);
            wv = (n < N) ? *(const float4*)(W + (size_t)n * ldw + (size_t)kt1 * 8 + lk)
                         : make_float4(0.f, 0.f, 0.f, 0.f);
        }
        #pragma unroll
        for (int k = 0; k < 8; ++k) {
            float a[8], b[8];
            #pragma unroll
            for (int i = 0; i < 8; ++i) a[i] = As[k][ty + 16 * i];
            #pragma unroll
            for (int j = 0; j < 8; ++j) b[j] = Bs[k][tx + 16 * j];
            #pragma unroll
            for (int i = 0; i < 8; ++i)
                #pragma unroll
                for (int j = 0; j < 8; ++j)
                    acc[i][j] = fmaf(a[i], b[j], acc[i][j]);
        }
    }
    #pragma unroll
    for (int i = 0; i < 8; ++i) {
        int m = bm0 + ty + 16 * i;
        #pragma unroll
        for (int j = 0; j < 8; ++j) {
            int n = bn0 + tx + 16 * j;
            if (n < N) C[(size_t)m * ldc + n] = acc[i][j];
        }
    }
}

// ---- reduce split-K partials ----
__global__ __launch_bounds__(256) void sk_reduce_kernel(
        const float* __restrict__ part, float* __restrict__ out, int total) {
    int i = blockIdx.x * 256 + threadIdx.x;
    if (i >= total) return;
    float s = 0.f;
    #pragma unroll
    for (int sk = 0; sk < SKX; ++sk) s += part[(size_t)sk * total + i];
    out[i] = s;
}

// ---- depthwise causal conv(4) + bias + SiLU ----
__global__ __launch_bounds__(256) void conv_silu_kernel(
        const float* __restrict__ xz, const float* __restrict__ cw,
        const float* __restrict__ cb, float* __restrict__ u) {
    int idx = blockIdx.x * 256 + threadIdx.x;
    int d  = idx & (D_INNER - 1);
    int bl = idx >> 11;
    int l  = bl & (SEQLEN - 1);
    const float* base = xz + (size_t)bl * 4096 + d;
    float4 w = *(const float4*)(cw + d * 4);
    float s = cb[d];
    if (l >= 3) s = fmaf(base[-3 * 4096], w.x, s);
    if (l >= 2) s = fmaf(base[-2 * 4096], w.y, s);
    if (l >= 1) s = fmaf(base[-1 * 4096], w.z, s);
    s = fmaf(base[0], w.w, s);
    u[idx] = s * __builtin_amdgcn_rcpf(1.f + __expf(-s));
}

// ================= chunk-parallel selective scan (per-thread h[16]) ========
__global__ __launch_bounds__(256) void scan_partA(
        const float* __restrict__ delta, const float* __restrict__ u,
        const float* __restrict__ xdbl, const float* __restrict__ A_log,
        float* __restrict__ hF, float* __restrict__ sumd) {
    const int tid = threadIdx.x;
    const int bx  = blockIdx.x;
    const int seg = bx >> 4;
    const int b   = (bx >> 3) & 1;
    const int d   = (bx & 7) * 256 + tid;
    const int t0  = seg * TSEG;
    float An2[16];
    #pragma unroll
    for (int q = 0; q < 4; ++q) {
        float4 a = *(const float4*)(A_log + d * 16 + q * 4);
        An2[q*4+0] = -__expf(a.x) * LOG2E;
        An2[q*4+1] = -__expf(a.y) * LOG2E;
        An2[q*4+2] = -__expf(a.z) * LOG2E;
        An2[q*4+3] = -__expf(a.w) * LOG2E;
    }
    const float* dl = delta + ((size_t)b * SEQLEN + t0) * D_INNER + d;
    const float* uu = u     + ((size_t)b * SEQLEN + t0) * D_INNER + d;
    const float* bc = xdbl  + ((size_t)b * SEQLEN + t0) * 96 + 64;
    float h[16];
    #pragma unroll
    for (int n = 0; n < 16; ++n) h[n] = 0.f;
    float sd = 0.f;
    float pdv[4], puv[4];
    #pragma unroll
    for (int j = 0; j < 4; ++j) {
        pdv[j] = dl[(size_t)j * D_INNER];
        puv[j] = uu[(size_t)j * D_INNER];
    }
    for (int t4 = 0; t4 < TSEG; t4 += 4) {
        #pragma unroll
        for (int j = 0; j < 4; ++j) {
            const float dv = pdv[j], uv = puv[j];
            if (t4 + 4 < TSEG) {
                pdv[j] = dl[(size_t)(t4 + 4 + j) * D_INNER];
                puv[j] = uu[(size_t)(t4 + 4 + j) * D_INNER];
            }
            const float* bct = bc + (size_t)(t4 + j) * 96;
            float4 B0 = *(const float4*)(bct);
            float4 B1 = *(const float4*)(bct + 4);
            float4 B2 = *(const float4*)(bct + 8);
            float4 B3 = *(const float4*)(bct + 12);
            float Bv[16] = {B0.x,B0.y,B0.z,B0.w, B1.x,B1.y,B1.z,B1.w,
                            B2.x,B2.y,B2.z,B2.w, B3.x,B3.y,B3.z,B3.w};
            const float dvuv = dv * uv;
            sd += dv;
            #pragma unroll
            for (int n = 0; n < 16; ++n)
                h[n] = fmaf(exp2f(dv * An2[n]), h[n], dvuv * Bv[n]);
        }
    }
    const size_t o = (size_t)seg * (BATCH * D_INNER) + (size_t)b * D_INNER + d;
    #pragma unroll
    for (int q = 0; q < 4; ++q)
        *(float4*)(hF + o * 16 + q * 4) =
            make_float4(h[q*4], h[q*4+1], h[q*4+2], h[q*4+3]);
    sumd[o] = sd;
}

__global__ __launch_bounds__(256) void scan_combine(
        const float* __restrict__ A_log, float* __restrict__ hFin,
        const float* __restrict__ sumd) {
    int idx = blockIdx.x * 256 + threadIdx.x;
    int n = idx & 15, row = idx >> 4;
    int d = row & (D_INNER - 1);
    float An = -__expf(A_log[d * 16 + n]);
    float f[NSEG], p[NSEG];
    #pragma unroll
    for (int s = 0; s < NSEG; ++s) {
        size_t o = (size_t)s * (BATCH * D_INNER) + row;
        f[s] = hFin[o * 16 + n];
        p[s] = __expf(An * sumd[o]);
    }
    float h = 0.f;
    #pragma unroll
    for (int s = 0; s < NSEG; ++s) {
        size_t o = (size_t)s * (BATCH * D_INNER) + row;
        hFin[o * 16 + n] = h;
        h = fmaf(p[s], h, f[s]);
    }
}

__global__ __launch_bounds__(256) void scan_partB(
        const float* delta, const float* __restrict__ u,
        const float* __restrict__ xdbl, const float* __restrict__ xz,
        const float* __restrict__ A_log, const float* __restrict__ Dp,
        const float* __restrict__ hin, float* yg) {
    const int tid = threadIdx.x;
    const int bx  = blockIdx.x;
    const int seg = bx >> 4;
    const int b   = (bx >> 3) & 1;
    const int d   = (bx & 7) * 256 + tid;
    const int t0  = seg * TSEG;
    float An2[16];
    #pragma unroll
    for (int q = 0; q < 4; ++q) {
        float4 a = *(const float4*)(A_log + d * 16 + q * 4);
        An2[q*4+0] = -__expf(a.x) * LOG2E;
        An2[q*4+1] = -__expf(a.y) * LOG2E;
        An2[q*4+2] = -__expf(a.z) * LOG2E;
        An2[q*4+3] = -__expf(a.w) * LOG2E;
    }
    const float Dd = Dp[d];
    const float* dl = delta + ((size_t)b * SEQLEN + t0) * D_INNER + d;
    const float* uu = u     + ((size_t)b * SEQLEN + t0) * D_INNER + d;
    const float* bc = xdbl  + ((size_t)b * SEQLEN + t0) * 96 + 64;
    const float* zz = xz    + ((size_t)b * SEQLEN + t0) * 4096 + D_INNER + d;
    float* yo = yg + ((size_t)b * SEQLEN + t0) * D_INNER + d;
    const size_t o = (size_t)seg * (BATCH * D_INNER) + (size_t)b * D_INNER + d;
    float h[16];
    #pragma unroll
    for (int q = 0; q < 4; ++q) {
        float4 hv = *(const float4*)(hin + o * 16 + q * 4);
        h[q*4] = hv.x; h[q*4+1] = hv.y; h[q*4+2] = hv.z; h[q*4+3] = hv.w;
    }
    float pdv[4], puv[4], pzv[4];
    #pragma unroll
    for (int j = 0; j < 4; ++j) {
        pdv[j] = dl[(size_t)j * D_INNER];
        puv[j] = uu[(size_t)j * D_INNER];
        pzv[j] = zz[(size_t)j * 4096];
    }
    for (int t4 = 0; t4 < TSEG; t4 += 4) {
        #pragma unroll
        for (int j = 0; j < 4; ++j) {
            const float dv = pdv[j], uv = puv[j], zv = pzv[j];
            if (t4 + 4 < TSEG) {
                pdv[j] = dl[(size_t)(t4 + 4 + j) * D_INNER];
                puv[j] = uu[(size_t)(t4 + 4 + j) * D_INNER];
                pzv[j] = zz[(size_t)(t4 + 4 + j) * 4096];
            }
            const float* bct = bc + (size_t)(t4 + j) * 96;
            float4 B0 = *(const float4*)(bct);
            float4 B1 = *(const float4*)(bct + 4);
            float4 B2 = *(const float4*)(bct + 8);
            float4 B3 = *(const float4*)(bct + 12);
            float4 C0 = *(const float4*)(bct + 16);
            float4 C1 = *(const float4*)(bct + 20);
            float4 C2 = *(const float4*)(bct + 24);
            float4 C3 = *(const float4*)(bct + 28);
            float Bv[16] = {B0.x,B0.y,B0.z,B0.w, B1.x,B1.y,B1.z,B1.w,
                            B2.x,B2.y,B2.z,B2.w, B3.x,B3.y,B3.z,B3.w};
            float Cv[16] = {C0.x,C0.y,C0.z,C0.w, C1.x,C1.y,C1.z,C1.w,
                            C2.x,C2.y,C2.z,C2.w, C3.x,C3.y,C3.z,C3.w};
            const float dvuv = dv * uv;
            #pragma unroll
            for (int n = 0; n < 16; ++n)
                h[n] = fmaf(exp2f(dv * An2[n]), h[n], dvuv * Bv[n]);
            float acc[4] = {0.f, 0.f, 0.f, 0.f};
            #pragma unroll
            for (int n = 0; n < 16; ++n)
                acc[n & 3] = fmaf(h[n], Cv[n], acc[n & 3]);
            float yv = fmaf(uv, Dd, (acc[0] + acc[1]) + (acc[2] + acc[3]));
            float sig = zv * __builtin_amdgcn_rcpf(1.f + __expf(-zv));
            yo[(size_t)(t4 + j) * D_INNER] = yv * sig;
        }
    }
}

extern "C" void kernel_launch(void* const* d_in, const int* in_sizes, int n_in,
                              void* d_out, int out_size, void* d_ws, size_t ws_size,
                              hipStream_t stream) {
    const float* x        = (const float*)d_in[0];
    const float* w_in     = (const float*)d_in[1];
    const float* lA_in    = (const float*)d_in[2];
    const float* lB_in    = (const float*)d_in[3];
    const float* mask_in  = (const float*)d_in[4];
    const float* conv_w   = (const float*)d_in[5];
    const float* conv_b   = (const float*)d_in[6];
    const float* w_xp     = (const float*)d_in[7];
    const float* w_dt     = (const float*)d_in[8];
    const float* b_dt     = (const float*)d_in[9];
    const float* A_log    = (const float*)d_in[10];
    const float* Dp       = (const float*)d_in[11];
    const float* w_out    = (const float*)d_in[12];
    const float* lA_out   = (const float*)d_in[13];
    const float* lB_out   = (const float*)d_in[14];
    const float* mask_out = (const float*)d_in[15];

    // f32 workspace layout
    float* ws    = (float*)d_ws;
    float* xz    = ws;                              // [BL,4096]
    float* u     = xz    + (size_t)BL * 4096;       // [BL,2048]
    float* delta = u     + (size_t)BL * D_INNER;    // [BL,2048] (also yg)
    float* xdbl  = delta + (size_t)BL * D_INNER;    // [BL,96]
    float* t16   = xdbl  + (size_t)BL * 96;         // [BL,16]
    float* lbin  = t16   + (size_t)BL * 16;         // [4096,16]
    float* lbout = lbin  + (size_t)4096 * 16;       // [1024,16]

    // bf16 arenas in dead f32 regions
    const size_t AS_IN = (size_t)4096 * 1056, WS_IN = (size_t)4096 * 1056;
    unsigned short* Ahi_in = (unsigned short*)u;
    unsigned short* Alo_in = Ahi_in + AS_IN;
    unsigned short* Whi_in = Alo_in + AS_IN;
    unsigned short* Wlo_in = Whi_in + WS_IN;

    unsigned short* dtb = (unsigned short*)d_out;
    unsigned short* Ahi_dt = dtb;
    unsigned short* Alo_dt = Ahi_dt + (size_t)4096 * 64;
    unsigned short* Whi_dt = Alo_dt + (size_t)4096 * 64;
    unsigned short* Wlo_dt = Whi_dt + (size_t)2048 * 64;

    const size_t AS_OUT = (size_t)4096 * 2080, WS_OUT = (size_t)1024 * 2080;
    unsigned short* Ahi_out = (unsigned short*)xz;
    unsigned short* Alo_out = Ahi_out + AS_OUT;
    unsigned short* Whi_out = Alo_out + AS_OUT;
    unsigned short* Wlo_out = Whi_out + WS_OUT;

    // d_out f32 scratch (pre-final uses)
    float* outf    = (float*)d_out;
    float* xp_part = outf;                                  // [SKX][BL*96]
    float* hFin    = outf;                                  // [NSEG][4096][16]
    float* sumd    = hFin + (size_t)NSEG * BATCH * D_INNER * 16;

    // 1) LoRA premultiply + t16_in
    premul_kernel<<<(4096 * 16 + 255) / 256, 256, 0, stream>>>(lB_in, mask_in, lbin, 4096 * 16);
    premul_kernel<<<(1024 * 16 + 255) / 256, 256, 0, stream>>>(lB_out, mask_out, lbout, 1024 * 16);
    lora_t_kernel<<<BL, 256, 0, stream>>>(x, D_MODEL, lA_in, D_MODEL, t16);
    // 2) hi/lo conversions for in_proj (K=1024, KP=1056)
    hilo_kernel<<<4096, 256, 0, stream>>>(x,    1024, 256, 1056, Ahi_in, Alo_in, 4096 * 256);
    hilo_kernel<<<4096, 256, 0, stream>>>(w_in, 1024, 256, 1056, Whi_in, Wlo_in, 4096 * 256);
    ext_kernel<<<512, 256, 0, stream>>>(t16,  1024, 1056, Ahi_in, Alo_in, 4096);
    ext_kernel<<<512, 256, 0, stream>>>(lbin, 1024, 1056, Whi_in, Wlo_in, 4096);
    // 3) in_proj MFMA GEMM -> xz
    mfma_gemm<0><<<dim3(32, 32), 256, 0, stream>>>(
        Ahi_in, Alo_in, Whi_in, Wlo_in, 1056, xz, 4096, nullptr);
    // 4) u = silu(conv(xs) + b)
    conv_silu_kernel<<<(BL * D_INNER) / 256, 256, 0, stream>>>(xz, conv_w, conv_b, u);
    // 5) x_proj split-K fp32 -> xdbl
    gemm_f32_kernel<<<dim3(1, BL / 128, SKX), 256, 0, stream>>>(
        u, D_INNER, w_xp, D_INNER, xp_part, 96, BL, 96, KCH, KCH);
    sk_reduce_kernel<<<(BL * 96 + 255) / 256, 256, 0, stream>>>(xp_part, xdbl, BL * 96);
    // 6) dt_proj MFMA (K=64) -> delta = softplus(. + b_dt)
    hilo_kernel<<<(4096 * 16 + 255) / 256, 256, 0, stream>>>(xdbl, 96, 16, 64, Ahi_dt, Alo_dt, 4096 * 16);
    hilo_kernel<<<(2048 * 16 + 255) / 256, 256, 0, stream>>>(w_dt, 64, 16, 64, Whi_dt, Wlo_dt, 2048 * 16);
    mfma_gemm<2><<<dim3(16, 32), 256, 0, stream>>>(
        Ahi_dt, Alo_dt, Whi_dt, Wlo_dt, 64, delta, 2048, b_dt);
    // 7) chunk-parallel selective scan (+ gating); yg aliases delta
    scan_partA<<<NSEG * BATCH * 8, 256, 0, stream>>>(delta, u, xdbl, A_log, hFin, sumd);
    scan_combine<<<(BATCH * D_INNER * 16) / 256, 256, 0, stream>>>(A_log, hFin, sumd);
    scan_partB<<<NSEG * BATCH * 8, 256, 0, stream>>>(delta, u, xdbl, xz, A_log, Dp, hFin, delta);
    // 8) out_proj: t16_out, conversions (K=2048, KP=2080), MFMA -> d_out
    lora_t_kernel<<<BL, 256, 0, stream>>>(delta, D_INNER, lA_out, D_INNER, t16);
    hilo_kernel<<<8192, 256, 0, stream>>>(delta, 2048, 512, 2080, Ahi_out, Alo_out, 4096 * 512);
    hilo_kernel<<<2048, 256, 0, stream>>>(w_out, 2048, 512, 2080, Whi_out, Wlo_out, 1024 * 512);
    ext_kernel<<<512, 256, 0, stream>>>(t16,   2048, 2080, Ahi_out, Alo_out, 4096);
    ext_kernel<<<128, 256, 0, stream>>>(lbout, 2048, 2080, Whi_out, Wlo_out, 1024);
    mfma_gemm<0><<<dim3(8, 32), 256, 0, stream>>>(
        Ahi_out, Alo_out, Whi_out, Wlo_out, 2080, (float*)d_out, 1024, nullptr);
}

// Round 8
// 544.782 us; speedup vs baseline: 1.3010x; 1.3010x over previous
//
#include <hip/hip_runtime.h>
#include <hip/hip_bf16.h>
#include <hip/hip_fp16.h>
#include <cstdint>
#include <cstddef>

// Problem constants (from reference)
#define D_MODEL 1024
#define D_INNER 2048
#define NSTATE  16
#define DTRANK  64
#define BATCH   2
#define SEQLEN  2048
#define BL      (BATCH*SEQLEN)   // 4096 tokens
#define NSEG    32
#define TSEG    (SEQLEN/NSEG)    // 64
#define SKX     8                // split-K factor for x_proj
#define KCH     (D_INNER/SKX)    // 256
#define LOG2E   1.4426950408889634f

typedef __attribute__((ext_vector_type(8))) short s16x8;
typedef __attribute__((ext_vector_type(8))) _Float16 f16x8;
typedef __attribute__((ext_vector_type(4))) float f32x4;

__device__ __forceinline__ float softplusf(float x) {
    return fmaxf(x, 0.f) + log1pf(expf(-fabsf(x)));
}
__device__ __forceinline__ unsigned short f2bf(float x) {
    __hip_bfloat16 b = __float2bfloat16(x);
    return *(unsigned short*)&b;
}
__device__ __forceinline__ float bf2f(unsigned short u) {
    __hip_bfloat16 b; *(unsigned short*)&b = u;
    return __bfloat162float(b);
}
__device__ __forceinline__ unsigned short f2h(float x) {
    __half h = __float2half(x);
    return *(unsigned short*)&h;
}
// async global->LDS, 16B per lane (dest must be linear: base + lane*16)
__device__ __forceinline__ void gll16(const void* g, void* l) {
    __builtin_amdgcn_global_load_lds(
        (const __attribute__((address_space(1))) void*)g,
        (__attribute__((address_space(3))) void*)l, 16, 0, 0);
}

// ---- lbp[n,r] = lora_B[n,r] * mask[n] * 2.0 ----
__global__ __launch_bounds__(256) void premul_kernel(
        const float* __restrict__ lb, const float* __restrict__ mask,
        float* __restrict__ out, int total) {
    int i = blockIdx.x * 256 + threadIdx.x;
    if (i < total) out[i] = lb[i] * mask[i >> 4] * 2.0f;
}

// ---- T[m,r] = sum_k X[m,k] * LA[r,k]   (r < 16) ----
__global__ __launch_bounds__(256) void lora_t_kernel(
        const float* __restrict__ X, int ldx,
        const float* __restrict__ LA, int K,
        float* __restrict__ T) {
    int m = blockIdx.x;
    int r = threadIdx.x >> 4;
    int l = threadIdx.x & 15;
    const float* xrow = X + (size_t)m * ldx;
    const float* arow = LA + (size_t)r * K;
    float s = 0.f;
    for (int k = 4 * l; k < K; k += 64) {
        float4 xv = *(const float4*)(xrow + k);
        float4 av = *(const float4*)(arow + k);
        s += xv.x * av.x + xv.y * av.y + xv.z * av.z + xv.w * av.w;
    }
    #pragma unroll
    for (int o = 8; o; o >>= 1) s += __shfl_xor(s, o, 16);
    if (l == 0) T[(size_t)m * 16 + r] = s;
}

// ---- hi/lo bf16 split: hi=bf16(v), lo=bf16(v-hi) ----
__global__ __launch_bounds__(256) void hilo_kernel(
        const float* __restrict__ src, int lda, int K4, int KP,
        unsigned short* __restrict__ hi, unsigned short* __restrict__ lo,
        int total4) {
    int idx = blockIdx.x * 256 + threadIdx.x;
    if (idx >= total4) return;
    int m = idx / K4;
    int kq = idx - m * K4;
    float4 v = *(const float4*)(src + (size_t)m * lda + kq * 4);
    ushort4 h, l;
    h.x = f2bf(v.x); l.x = f2bf(v.x - bf2f(h.x));
    h.y = f2bf(v.y); l.y = f2bf(v.y - bf2f(h.y));
    h.z = f2bf(v.z); l.z = f2bf(v.z - bf2f(h.z));
    h.w = f2bf(v.w); l.w = f2bf(v.w - bf2f(h.w));
    *(ushort4*)(hi + (size_t)m * KP + kq * 4) = h;
    *(ushort4*)(lo + (size_t)m * KP + kq * 4) = l;
}

// ---- fp16 convert: dst[m][k] = fp16(src[m][k]) ----
__global__ __launch_bounds__(256) void cvt16_kernel(
        const float* __restrict__ src, int lda, int K4, int KP,
        unsigned short* __restrict__ dst, int total4) {
    int idx = blockIdx.x * 256 + threadIdx.x;
    if (idx >= total4) return;
    int m = idx / K4;
    int kq = idx - m * K4;
    float4 v = *(const float4*)(src + (size_t)m * lda + kq * 4);
    ushort4 h;
    h.x = f2h(v.x); h.y = f2h(v.y); h.z = f2h(v.z); h.w = f2h(v.w);
    *(ushort4*)(dst + (size_t)m * KP + kq * 4) = h;
}

// ---- LoRA K-extension columns (bf16 hi/lo) ----
__global__ __launch_bounds__(256) void ext_kernel(
        const float* __restrict__ t16, int K, int KP,
        unsigned short* __restrict__ hi, unsigned short* __restrict__ lo,
        int M) {
    int idx = blockIdx.x * 256 + threadIdx.x;
    if (idx >= M * 32) return;
    int c = idx & 31, m = idx >> 5;
    unsigned short hv = 0;
    if (c < 16) hv = f2bf(t16[(size_t)m * 16 + c]);
    hi[(size_t)m * KP + K + c] = hv;
    lo[(size_t)m * KP + K + c] = 0;
}

// ---- LoRA K-extension columns (fp16 single) ----
__global__ __launch_bounds__(256) void ext16_kernel(
        const float* __restrict__ t16, int K, int KP,
        unsigned short* __restrict__ dst, int M) {
    int idx = blockIdx.x * 256 + threadIdx.x;
    if (idx >= M * 32) return;
    int c = idx & 31, m = idx >> 5;
    unsigned short hv = 0;
    if (c < 16) hv = f2h(t16[(size_t)m * 16 + c]);
    dst[(size_t)m * KP + K + c] = hv;
}

// ---- fp16 single-pass MFMA GEMM, 2-phase dbuf (round-5 structure) ----
template<int EPI>
__global__ __launch_bounds__(256, 4) void mfma_gemm16(
        const unsigned short* __restrict__ Ag, const unsigned short* __restrict__ Wg,
        int KP, float* __restrict__ C, int ldc,
        const float* __restrict__ bias) {
    __shared__ __align__(16) short Ash[2][4][128][8];
    __shared__ __align__(16) short Wsh[2][4][128][8];
    const int tid = threadIdx.x;
    const int bn0 = blockIdx.x * 128, bm0 = blockIdx.y * 128;
    const int wave = tid >> 6, lane = tid & 63;
    const int wr = (wave >> 1) * 64, wc = (wave & 1) * 64;
    const int fr = lane & 15, fg = lane >> 4;
    const int KT = KP >> 5;
    const int srow = tid & 127, skg = tid >> 7;

    const unsigned short* pA = Ag + (size_t)(bm0 + srow) * KP + skg * 8;
    const unsigned short* pW = Wg + (size_t)(bn0 + srow) * KP + skg * 8;

    f32x4 acc[4][4];
    #pragma unroll
    for (int i = 0; i < 4; ++i)
        #pragma unroll
        for (int j = 0; j < 4; ++j) acc[i][j] = (f32x4){0.f, 0.f, 0.f, 0.f};

    auto stage = [&](int kt, int pb) {
        const int koff = kt * 32;
        gll16(pA + koff,      &Ash[pb][skg    ][srow][0]);
        gll16(pA + koff + 16, &Ash[pb][skg + 2][srow][0]);
        gll16(pW + koff,      &Wsh[pb][skg    ][srow][0]);
        gll16(pW + koff + 16, &Wsh[pb][skg + 2][srow][0]);
    };

    stage(0, 0);
    for (int kt = 0; kt < KT; ++kt) {
        const int cur = kt & 1;
        __syncthreads();   // drains vmcnt(0): buf[cur] staged; prev reads done
        if (kt + 1 < KT) stage(kt + 1, cur ^ 1);
        f16x8 a[4], w[4];
        #pragma unroll
        for (int i = 0; i < 4; ++i) {
            a[i] = *(const f16x8*)&Ash[cur][fg][wr + i * 16 + fr][0];
            w[i] = *(const f16x8*)&Wsh[cur][fg][wc + i * 16 + fr][0];
        }
        #pragma unroll
        for (int i = 0; i < 4; ++i)
            #pragma unroll
            for (int j = 0; j < 4; ++j)
                acc[i][j] = __builtin_amdgcn_mfma_f32_16x16x32_f16(a[i], w[j], acc[i][j], 0, 0, 0);
    }
    // C/D layout: col = lane&15, row = (lane>>4)*4 + q
    #pragma unroll
    for (int i = 0; i < 4; ++i) {
        #pragma unroll
        for (int j = 0; j < 4; ++j) {
            int n = bn0 + wc + j * 16 + fr;
            #pragma unroll
            for (int q = 0; q < 4; ++q) {
                int m = bm0 + wr + i * 16 + fg * 4 + q;
                float v = acc[i][j][q];
                if (EPI == 2) v = softplusf(v + bias[n]);
                C[(size_t)m * ldc + n] = v;
            }
        }
    }
}

// ---- hi/lo bf16 3-pass MFMA GEMM, 2-phase dbuf (round-5 structure) ----
template<int EPI>
__global__ __launch_bounds__(256, 2) void mfma_gemm(
        const unsigned short* __restrict__ Ahg, const unsigned short* __restrict__ Alg,
        const unsigned short* __restrict__ Whg, const unsigned short* __restrict__ Wlg,
        int KP, float* __restrict__ C, int ldc,
        const float* __restrict__ bias) {
    __shared__ __align__(16) short Ash[2][4][128][8];
    __shared__ __align__(16) short Asl[2][4][128][8];
    __shared__ __align__(16) short Wsh[2][4][128][8];
    __shared__ __align__(16) short Wsl[2][4][128][8];
    const int tid = threadIdx.x;
    const int bn0 = blockIdx.x * 128, bm0 = blockIdx.y * 128;
    const int wave = tid >> 6, lane = tid & 63;
    const int wr = (wave >> 1) * 64, wc = (wave & 1) * 64;
    const int fr = lane & 15, fg = lane >> 4;
    const int KT = KP >> 5;
    const int srow = tid & 127, skg = tid >> 7;

    const unsigned short* pAh = Ahg + (size_t)(bm0 + srow) * KP + skg * 8;
    const unsigned short* pAl = Alg + (size_t)(bm0 + srow) * KP + skg * 8;
    const unsigned short* pWh = Whg + (size_t)(bn0 + srow) * KP + skg * 8;
    const unsigned short* pWl = Wlg + (size_t)(bn0 + srow) * KP + skg * 8;

    f32x4 acc[4][4];
    #pragma unroll
    for (int i = 0; i < 4; ++i)
        #pragma unroll
        for (int j = 0; j < 4; ++j) acc[i][j] = (f32x4){0.f, 0.f, 0.f, 0.f};

    auto stage = [&](int kt, int pb) {
        const int koff = kt * 32;
        gll16(pAh + koff,      &Ash[pb][skg    ][srow][0]);
        gll16(pAh + koff + 16, &Ash[pb][skg + 2][srow][0]);
        gll16(pAl + koff,      &Asl[pb][skg    ][srow][0]);
        gll16(pAl + koff + 16, &Asl[pb][skg + 2][srow][0]);
        gll16(pWh + koff,      &Wsh[pb][skg    ][srow][0]);
        gll16(pWh + koff + 16, &Wsh[pb][skg + 2][srow][0]);
        gll16(pWl + koff,      &Wsl[pb][skg    ][srow][0]);
        gll16(pWl + koff + 16, &Wsl[pb][skg + 2][srow][0]);
    };

    stage(0, 0);
    for (int kt = 0; kt < KT; ++kt) {
        const int cur = kt & 1;
        __syncthreads();   // drains vmcnt(0): buf[cur] staged; prev reads done
        if (kt + 1 < KT) stage(kt + 1, cur ^ 1);
        s16x8 ah[4], al[4], wh[4], wl[4];
        #pragma unroll
        for (int i = 0; i < 4; ++i) {
            ah[i] = *(const s16x8*)&Ash[cur][fg][wr + i * 16 + fr][0];
            al[i] = *(const s16x8*)&Asl[cur][fg][wr + i * 16 + fr][0];
            wh[i] = *(const s16x8*)&Wsh[cur][fg][wc + i * 16 + fr][0];
            wl[i] = *(const s16x8*)&Wsl[cur][fg][wc + i * 16 + fr][0];
        }
        #pragma unroll
        for (int i = 0; i < 4; ++i)
            #pragma unroll
            for (int j = 0; j < 4; ++j) {
                acc[i][j] = __builtin_amdgcn_mfma_f32_16x16x32_bf16(ah[i], wh[j], acc[i][j], 0, 0, 0);
                acc[i][j] = __builtin_amdgcn_mfma_f32_16x16x32_bf16(ah[i], wl[j], acc[i][j], 0, 0, 0);
                acc[i][j] = __builtin_amdgcn_mfma_f32_16x16x32_bf16(al[i], wh[j], acc[i][j], 0, 0, 0);
            }
    }
    // C/D layout: col = lane&15, row = (lane>>4)*4 + q
    #pragma unroll
    for (int i = 0; i < 4; ++i) {
        #pragma unroll
        for (int j = 0; j < 4; ++j) {
            int n = bn0 + wc + j * 16 + fr;
            #pragma unroll
            for (int q = 0; q < 4; ++q) {
                int m = bm0 + wr + i * 16 + fg * 4 + q;
                float v = acc[i][j][q];
                if (EPI == 2) v = softplusf(v + bias[n]);
                C[(size_t)m * ldc + n] = v;
            }
        }
    }
}

// ---- fp32 tiled GEMM (x_proj split-K; N=96) ----
__global__ __launch_bounds__(256) void gemm_f32_kernel(
        const float* __restrict__ A, int lda,
        const float* __restrict__ W, int ldw,
        float* __restrict__ C, int ldc,
        int M, int N, int K, int kchunk) {
    __shared__ float As[8][128];
    __shared__ float Bs[8][128];
    if (kchunk) {
        A += (size_t)blockIdx.z * kchunk;
        W += (size_t)blockIdx.z * kchunk;
        C += (size_t)blockIdx.z * M * ldc;
    }
    const int tid = threadIdx.x;
    const int tx = tid & 15, ty = tid >> 4;
    const int bn0 = blockIdx.x * 128, bm0 = blockIdx.y * 128;
    const int lrow = tid >> 1;
    const int lk   = (tid & 1) * 4;
    const int nk = K >> 3;

    float acc[8][8];
    #pragma unroll
    for (int i = 0; i < 8; ++i)
        #pragma unroll
        for (int j = 0; j < 8; ++j) acc[i][j] = 0.f;

    float4 av, wv;
    {
        av = *(const float4*)(A + (size_t)(bm0 + lrow) * lda + lk);
        int n = bn0 + lrow;
        wv = (n < N) ? *(const float4*)(W + (size_t)n * ldw + lk)
                     : make_float4(0.f, 0.f, 0.f, 0.f);
    }
    for (int kt = 0; kt < nk; ++kt) {
        __syncthreads();
        As[lk + 0][lrow] = av.x; As[lk + 1][lrow] = av.y;
        As[lk + 2][lrow] = av.z; As[lk + 3][lrow] = av.w;
        Bs[lk + 0][lrow] = wv.x; Bs[lk + 1][lrow] = wv.y;
        Bs[lk + 2][lrow] = wv.z; Bs[lk + 3][lrow] = wv.w;
        __syncthreads();
        int kt1 = kt + 1;
        if (kt1 < nk) {
            int n = bn0 + lrow;
            av = *(const float4*)(A + (size_t)(bm0 + lrow) * lda + (size_t)kt1 * 8 + lk);
            wv = (n < N) ? *(const float4*)(W + (size_t)n * ldw + (size_t)kt1 * 8 + lk)
                         : make_float4(0.f, 0.f, 0.f, 0.f);
        }
        #pragma unroll
        for (int k = 0; k < 8; ++k) {
            float a[8], b[8];
            #pragma unroll
            for (int i = 0; i < 8; ++i) a[i] = As[k][ty + 16 * i];
            #pragma unroll
            for (int j = 0; j < 8; ++j) b[j] = Bs[k][tx + 16 * j];
            #pragma unroll
            for (int i = 0; i < 8; ++i)
                #pragma unroll
                for (int j = 0; j < 8; ++j)
                    acc[i][j] = fmaf(a[i], b[j], acc[i][j]);
        }
    }
    #pragma unroll
    for (int i = 0; i < 8; ++i) {
        int m = bm0 + ty + 16 * i;
        #pragma unroll
        for (int j = 0; j < 8; ++j) {
            int n = bn0 + tx + 16 * j;
            if (n < N) C[(size_t)m * ldc + n] = acc[i][j];
        }
    }
}

// ---- reduce split-K partials ----
__global__ __launch_bounds__(256) void sk_reduce_kernel(
        const float* __restrict__ part, float* __restrict__ out, int total) {
    int i = blockIdx.x * 256 + threadIdx.x;
    if (i >= total) return;
    float s = 0.f;
    #pragma unroll
    for (int sk = 0; sk < SKX; ++sk) s += part[(size_t)sk * total + i];
    out[i] = s;
}

// ---- depthwise causal conv(4) + bias + SiLU ----
__global__ __launch_bounds__(256) void conv_silu_kernel(
        const float* __restrict__ xz, const float* __restrict__ cw,
        const float* __restrict__ cb, float* __restrict__ u) {
    int idx = blockIdx.x * 256 + threadIdx.x;
    int d  = idx & (D_INNER - 1);
    int bl = idx >> 11;
    int l  = bl & (SEQLEN - 1);
    const float* base = xz + (size_t)bl * 4096 + d;
    float4 w = *(const float4*)(cw + d * 4);
    float s = cb[d];
    if (l >= 3) s = fmaf(base[-3 * 4096], w.x, s);
    if (l >= 2) s = fmaf(base[-2 * 4096], w.y, s);
    if (l >= 1) s = fmaf(base[-1 * 4096], w.z, s);
    s = fmaf(base[0], w.w, s);
    u[idx] = s * __builtin_amdgcn_rcpf(1.f + __expf(-s));
}

// ================= chunk-parallel selective scan (per-thread h[16]) ========
__global__ __launch_bounds__(256) void scan_partA(
        const float* __restrict__ delta, const float* __restrict__ u,
        const float* __restrict__ xdbl, const float* __restrict__ A_log,
        float* __restrict__ hF, float* __restrict__ sumd) {
    const int tid = threadIdx.x;
    const int bx  = blockIdx.x;
    const int seg = bx >> 4;
    const int b   = (bx >> 3) & 1;
    const int d   = (bx & 7) * 256 + tid;
    const int t0  = seg * TSEG;
    float An2[16];
    #pragma unroll
    for (int q = 0; q < 4; ++q) {
        float4 a = *(const float4*)(A_log + d * 16 + q * 4);
        An2[q*4+0] = -__expf(a.x) * LOG2E;
        An2[q*4+1] = -__expf(a.y) * LOG2E;
        An2[q*4+2] = -__expf(a.z) * LOG2E;
        An2[q*4+3] = -__expf(a.w) * LOG2E;
    }
    const float* dl = delta + ((size_t)b * SEQLEN + t0) * D_INNER + d;
    const float* uu = u     + ((size_t)b * SEQLEN + t0) * D_INNER + d;
    const float* bc = xdbl  + ((size_t)b * SEQLEN + t0) * 96 + 64;
    float h[16];
    #pragma unroll
    for (int n = 0; n < 16; ++n) h[n] = 0.f;
    float sd = 0.f;
    float pdv[4], puv[4];
    #pragma unroll
    for (int j = 0; j < 4; ++j) {
        pdv[j] = dl[(size_t)j * D_INNER];
        puv[j] = uu[(size_t)j * D_INNER];
    }
    for (int t4 = 0; t4 < TSEG; t4 += 4) {
        #pragma unroll
        for (int j = 0; j < 4; ++j) {
            const float dv = pdv[j], uv = puv[j];
            if (t4 + 4 < TSEG) {
                pdv[j] = dl[(size_t)(t4 + 4 + j) * D_INNER];
                puv[j] = uu[(size_t)(t4 + 4 + j) * D_INNER];
            }
            const float* bct = bc + (size_t)(t4 + j) * 96;
            float4 B0 = *(const float4*)(bct);
            float4 B1 = *(const float4*)(bct + 4);
            float4 B2 = *(const float4*)(bct + 8);
            float4 B3 = *(const float4*)(bct + 12);
            float Bv[16] = {B0.x,B0.y,B0.z,B0.w, B1.x,B1.y,B1.z,B1.w,
                            B2.x,B2.y,B2.z,B2.w, B3.x,B3.y,B3.z,B3.w};
            const float dvuv = dv * uv;
            sd += dv;
            #pragma unroll
            for (int n = 0; n < 16; ++n)
                h[n] = fmaf(exp2f(dv * An2[n]), h[n], dvuv * Bv[n]);
        }
    }
    const size_t o = (size_t)seg * (BATCH * D_INNER) + (size_t)b * D_INNER + d;
    #pragma unroll
    for (int q = 0; q < 4; ++q)
        *(float4*)(hF + o * 16 + q * 4) =
            make_float4(h[q*4], h[q*4+1], h[q*4+2], h[q*4+3]);
    sumd[o] = sd;
}

__global__ __launch_bounds__(256) void scan_combine(
        const float* __restrict__ A_log, float* __restrict__ hFin,
        const float* __restrict__ sumd) {
    int idx = blockIdx.x * 256 + threadIdx.x;
    int n = idx & 15, row = idx >> 4;
    int d = row & (D_INNER - 1);
    float An = -__expf(A_log[d * 16 + n]);
    float f[NSEG], p[NSEG];
    #pragma unroll
    for (int s = 0; s < NSEG; ++s) {
        size_t o = (size_t)s * (BATCH * D_INNER) + row;
        f[s] = hFin[o * 16 + n];
        p[s] = __expf(An * sumd[o]);
    }
    float h = 0.f;
    #pragma unroll
    for (int s = 0; s < NSEG; ++s) {
        size_t o = (size_t)s * (BATCH * D_INNER) + row;
        hFin[o * 16 + n] = h;
        h = fmaf(p[s], h, f[s]);
    }
}

__global__ __launch_bounds__(256) void scan_partB(
        const float* delta, const float* __restrict__ u,
        const float* __restrict__ xdbl, const float* __restrict__ xz,
        const float* __restrict__ A_log, const float* __restrict__ Dp,
        const float* __restrict__ hin, float* yg) {
    const int tid = threadIdx.x;
    const int bx  = blockIdx.x;
    const int seg = bx >> 4;
    const int b   = (bx >> 3) & 1;
    const int d   = (bx & 7) * 256 + tid;
    const int t0  = seg * TSEG;
    float An2[16];
    #pragma unroll
    for (int q = 0; q < 4; ++q) {
        float4 a = *(const float4*)(A_log + d * 16 + q * 4);
        An2[q*4+0] = -__expf(a.x) * LOG2E;
        An2[q*4+1] = -__expf(a.y) * LOG2E;
        An2[q*4+2] = -__expf(a.z) * LOG2E;
        An2[q*4+3] = -__expf(a.w) * LOG2E;
    }
    const float Dd = Dp[d];
    const float* dl = delta + ((size_t)b * SEQLEN + t0) * D_INNER + d;
    const float* uu = u     + ((size_t)b * SEQLEN + t0) * D_INNER + d;
    const float* bc = xdbl  + ((size_t)b * SEQLEN + t0) * 96 + 64;
    const float* zz = xz    + ((size_t)b * SEQLEN + t0) * 4096 + D_INNER + d;
    float* yo = yg + ((size_t)b * SEQLEN + t0) * D_INNER + d;
    const size_t o = (size_t)seg * (BATCH * D_INNER) + (size_t)b * D_INNER + d;
    float h[16];
    #pragma unroll
    for (int q = 0; q < 4; ++q) {
        float4 hv = *(const float4*)(hin + o * 16 + q * 4);
        h[q*4] = hv.x; h[q*4+1] = hv.y; h[q*4+2] = hv.z; h[q*4+3] = hv.w;
    }
    float pdv[4], puv[4], pzv[4];
    #pragma unroll
    for (int j = 0; j < 4; ++j) {
        pdv[j] = dl[(size_t)j * D_INNER];
        puv[j] = uu[(size_t)j * D_INNER];
        pzv[j] = zz[(size_t)j * 4096];
    }
    for (int t4 = 0; t4 < TSEG; t4 += 4) {
        #pragma unroll
        for (int j = 0; j < 4; ++j) {
            const float dv = pdv[j], uv = puv[j], zv = pzv[j];
            if (t4 + 4 < TSEG) {
                pdv[j] = dl[(size_t)(t4 + 4 + j) * D_INNER];
                puv[j] = uu[(size_t)(t4 + 4 + j) * D_INNER];
                pzv[j] = zz[(size_t)(t4 + 4 + j) * 4096];
            }
            const float* bct = bc + (size_t)(t4 + j) * 96;
            float4 B0 = *(const float4*)(bct);
            float4 B1 = *(const float4*)(bct + 4);
            float4 B2 = *(const float4*)(bct + 8);
            float4 B3 = *(const float4*)(bct + 12);
            float4 C0 = *(const float4*)(bct + 16);
            float4 C1 = *(const float4*)(bct + 20);
            float4 C2 = *(const float4*)(bct + 24);
            float4 C3 = *(const float4*)(bct + 28);
            float Bv[16] = {B0.x,B0.y,B0.z,B0.w, B1.x,B1.y,B1.z,B1.w,
                            B2.x,B2.y,B2.z,B2.w, B3.x,B3.y,B3.z,B3.w};
            float Cv[16] = {C0.x,C0.y,C0.z,C0.w, C1.x,C1.y,C1.z,C1.w,
                            C2.x,C2.y,C2.z,C2.w, C3.x,C3.y,C3.z,C3.w};
            const float dvuv = dv * uv;
            #pragma unroll
            for (int n = 0; n < 16; ++n)
                h[n] = fmaf(exp2f(dv * An2[n]), h[n], dvuv * Bv[n]);
            float acc[4] = {0.f, 0.f, 0.f, 0.f};
            #pragma unroll
            for (int n = 0; n < 16; ++n)
                acc[n & 3] = fmaf(h[n], Cv[n], acc[n & 3]);
            float yv = fmaf(uv, Dd, (acc[0] + acc[1]) + (acc[2] + acc[3]));
            float sig = zv * __builtin_amdgcn_rcpf(1.f + __expf(-zv));
            yo[(size_t)(t4 + j) * D_INNER] = yv * sig;
        }
    }
}

extern "C" void kernel_launch(void* const* d_in, const int* in_sizes, int n_in,
                              void* d_out, int out_size, void* d_ws, size_t ws_size,
                              hipStream_t stream) {
    const float* x        = (const float*)d_in[0];
    const float* w_in     = (const float*)d_in[1];
    const float* lA_in    = (const float*)d_in[2];
    const float* lB_in    = (const float*)d_in[3];
    const float* mask_in  = (const float*)d_in[4];
    const float* conv_w   = (const float*)d_in[5];
    const float* conv_b   = (const float*)d_in[6];
    const float* w_xp     = (const float*)d_in[7];
    const float* w_dt     = (const float*)d_in[8];
    const float* b_dt     = (const float*)d_in[9];
    const float* A_log    = (const float*)d_in[10];
    const float* Dp       = (const float*)d_in[11];
    const float* w_out    = (const float*)d_in[12];
    const float* lA_out   = (const float*)d_in[13];
    const float* lB_out   = (const float*)d_in[14];
    const float* mask_out = (const float*)d_in[15];

    // f32 workspace layout
    float* ws    = (float*)d_ws;
    float* xz    = ws;                              // [BL,4096]
    float* u     = xz    + (size_t)BL * 4096;       // [BL,2048]
    float* delta = u     + (size_t)BL * D_INNER;    // [BL,2048] (also yg)
    float* xdbl  = delta + (size_t)BL * D_INNER;    // [BL,96]
    float* t16   = xdbl  + (size_t)BL * 96;         // [BL,16]
    float* lbin  = t16   + (size_t)BL * 16;         // [4096,16]
    float* lbout = lbin  + (size_t)4096 * 16;       // [1024,16]

    // fp16 arenas for in_proj in dead u region (17.3 MB < 33.5 MB)
    unsigned short* Ah16_in = (unsigned short*)u;                 // [4096][1056]
    unsigned short* Wh16_in = Ah16_in + (size_t)4096 * 1056;      // [4096][1056]

    // fp16 arenas for dt_proj in d_out scratch
    unsigned short* Ah16_dt = (unsigned short*)d_out;             // [4096][64]
    unsigned short* Wh16_dt = Ah16_dt + (size_t)4096 * 64;        // [2048][64]

    // bf16 hi/lo arenas for out_proj in dead xz region
    const size_t AS_OUT = (size_t)4096 * 2080, WS_OUT = (size_t)1024 * 2080;
    unsigned short* Ahi_out = (unsigned short*)xz;
    unsigned short* Alo_out = Ahi_out + AS_OUT;
    unsigned short* Whi_out = Alo_out + AS_OUT;
    unsigned short* Wlo_out = Whi_out + WS_OUT;

    // d_out f32 scratch (pre-final uses)
    float* outf    = (float*)d_out;
    float* xp_part = outf;                                  // [SKX][BL*96]
    float* hFin    = outf;                                  // [NSEG][4096][16]
    float* sumd    = hFin + (size_t)NSEG * BATCH * D_INNER * 16;

    // 1) LoRA premultiply + t16_in
    premul_kernel<<<(4096 * 16 + 255) / 256, 256, 0, stream>>>(lB_in, mask_in, lbin, 4096 * 16);
    premul_kernel<<<(1024 * 16 + 255) / 256, 256, 0, stream>>>(lB_out, mask_out, lbout, 1024 * 16);
    lora_t_kernel<<<BL, 256, 0, stream>>>(x, D_MODEL, lA_in, D_MODEL, t16);
    // 2) fp16 conversions for in_proj (K=1024, KP=1056 incl. LoRA ext)
    cvt16_kernel<<<4096, 256, 0, stream>>>(x,    1024, 256, 1056, Ah16_in, 4096 * 256);
    cvt16_kernel<<<4096, 256, 0, stream>>>(w_in, 1024, 256, 1056, Wh16_in, 4096 * 256);
    ext16_kernel<<<512, 256, 0, stream>>>(t16,  1024, 1056, Ah16_in, 4096);
    ext16_kernel<<<512, 256, 0, stream>>>(lbin, 1024, 1056, Wh16_in, 4096);
    // 3) in_proj fp16 MFMA GEMM -> xz
    mfma_gemm16<0><<<dim3(32, 32), 256, 0, stream>>>(
        Ah16_in, Wh16_in, 1056, xz, 4096, nullptr);
    // 4) u = silu(conv(xs) + b)
    conv_silu_kernel<<<(BL * D_INNER) / 256, 256, 0, stream>>>(xz, conv_w, conv_b, u);
    // 5) x_proj split-K fp32 -> xdbl
    gemm_f32_kernel<<<dim3(1, BL / 128, SKX), 256, 0, stream>>>(
        u, D_INNER, w_xp, D_INNER, xp_part, 96, BL, 96, KCH, KCH);
    sk_reduce_kernel<<<(BL * 96 + 255) / 256, 256, 0, stream>>>(xp_part, xdbl, BL * 96);
    // 6) dt_proj fp16 MFMA (K=64) -> delta = softplus(. + b_dt)
    cvt16_kernel<<<(4096 * 16 + 255) / 256, 256, 0, stream>>>(xdbl, 96, 16, 64, Ah16_dt, 4096 * 16);
    cvt16_kernel<<<(2048 * 16 + 255) / 256, 256, 0, stream>>>(w_dt, 64, 16, 64, Wh16_dt, 2048 * 16);
    mfma_gemm16<2><<<dim3(16, 32), 256, 0, stream>>>(
        Ah16_dt, Wh16_dt, 64, delta, 2048, b_dt);
    // 7) chunk-parallel selective scan (+ gating); yg aliases delta
    scan_partA<<<NSEG * BATCH * 8, 256, 0, stream>>>(delta, u, xdbl, A_log, hFin, sumd);
    scan_combine<<<(BATCH * D_INNER * 16) / 256, 256, 0, stream>>>(A_log, hFin, sumd);
    scan_partB<<<NSEG * BATCH * 8, 256, 0, stream>>>(delta, u, xdbl, xz, A_log, Dp, hFin, delta);
    // 8) out_proj: t16_out, bf16 hi/lo conversions (K=2048, KP=2080), MFMA -> d_out
    lora_t_kernel<<<BL, 256, 0, stream>>>(delta, D_INNER, lA_out, D_INNER, t16);
    hilo_kernel<<<8192, 256, 0, stream>>>(delta, 2048, 512, 2080, Ahi_out, Alo_out, 4096 * 512);
    hilo_kernel<<<2048, 256, 0, stream>>>(w_out, 2048, 512, 2080, Whi_out, Wlo_out, 1024 * 512);
    ext_kernel<<<512, 256, 0, stream>>>(t16,   2048, 2080, Ahi_out, Alo_out, 4096);
    ext_kernel<<<128, 256, 0, stream>>>(lbout, 2048, 2080, Whi_out, Wlo_out, 1024);
    mfma_gemm<0><<<dim3(8, 32), 256, 0, stream>>>(
        Ahi_out, Alo_out, Whi_out, Wlo_out, 2080, (float*)d_out, 1024, nullptr);
}

// Round 9
// 528.302 us; speedup vs baseline: 1.3416x; 1.0312x over previous
//
#include <hip/hip_runtime.h>
#include <hip/hip_bf16.h>
#include <hip/hip_fp16.h>
#include <cstdint>
#include <cstddef>

// Problem constants (from reference)
#define D_MODEL 1024
#define D_INNER 2048
#define NSTATE  16
#define DTRANK  64
#define BATCH   2
#define SEQLEN  2048
#define BL      (BATCH*SEQLEN)   // 4096 tokens
#define NSEG    32
#define TSEG    (SEQLEN/NSEG)    // 64
#define SKX     8                // split-K factor for x_proj
#define KCH     (D_INNER/SKX)    // 256
#define LOG2E   1.4426950408889634f

typedef __attribute__((ext_vector_type(8))) short s16x8;
typedef __attribute__((ext_vector_type(8))) _Float16 f16x8;
typedef __attribute__((ext_vector_type(4))) float f32x4;

__device__ __forceinline__ float softplusf(float x) {
    return fmaxf(x, 0.f) + log1pf(expf(-fabsf(x)));
}
__device__ __forceinline__ unsigned short f2bf(float x) {
    __hip_bfloat16 b = __float2bfloat16(x);
    return *(unsigned short*)&b;
}
__device__ __forceinline__ float bf2f(unsigned short u) {
    __hip_bfloat16 b; *(unsigned short*)&b = u;
    return __bfloat162float(b);
}
__device__ __forceinline__ unsigned short f2h(float x) {
    __half h = __float2half(x);
    return *(unsigned short*)&h;
}
// async global->LDS, 16B per lane (dest must be linear: base + lane*16)
__device__ __forceinline__ void gll16(const void* g, void* l) {
    __builtin_amdgcn_global_load_lds(
        (const __attribute__((address_space(1))) void*)g,
        (__attribute__((address_space(3))) void*)l, 16, 0, 0);
}

// ---- lbp[n,r] = lora_B[n,r] * mask[n] * 2.0 ----
__global__ __launch_bounds__(256) void premul_kernel(
        const float* __restrict__ lb, const float* __restrict__ mask,
        float* __restrict__ out, int total) {
    int i = blockIdx.x * 256 + threadIdx.x;
    if (i < total) out[i] = lb[i] * mask[i >> 4] * 2.0f;
}

// ---- T[m,r] = sum_k X[m,k] * LA[r,k]   (r < 16) ----
__global__ __launch_bounds__(256) void lora_t_kernel(
        const float* __restrict__ X, int ldx,
        const float* __restrict__ LA, int K,
        float* __restrict__ T) {
    int m = blockIdx.x;
    int r = threadIdx.x >> 4;
    int l = threadIdx.x & 15;
    const float* xrow = X + (size_t)m * ldx;
    const float* arow = LA + (size_t)r * K;
    float s = 0.f;
    for (int k = 4 * l; k < K; k += 64) {
        float4 xv = *(const float4*)(xrow + k);
        float4 av = *(const float4*)(arow + k);
        s += xv.x * av.x + xv.y * av.y + xv.z * av.z + xv.w * av.w;
    }
    #pragma unroll
    for (int o = 8; o; o >>= 1) s += __shfl_xor(s, o, 16);
    if (l == 0) T[(size_t)m * 16 + r] = s;
}

// ---- hi/lo bf16 split: hi=bf16(v), lo=bf16(v-hi) ----
__global__ __launch_bounds__(256) void hilo_kernel(
        const float* __restrict__ src, int lda, int K4, int KP,
        unsigned short* __restrict__ hi, unsigned short* __restrict__ lo,
        int total4) {
    int idx = blockIdx.x * 256 + threadIdx.x;
    if (idx >= total4) return;
    int m = idx / K4;
    int kq = idx - m * K4;
    float4 v = *(const float4*)(src + (size_t)m * lda + kq * 4);
    ushort4 h, l;
    h.x = f2bf(v.x); l.x = f2bf(v.x - bf2f(h.x));
    h.y = f2bf(v.y); l.y = f2bf(v.y - bf2f(h.y));
    h.z = f2bf(v.z); l.z = f2bf(v.z - bf2f(h.z));
    h.w = f2bf(v.w); l.w = f2bf(v.w - bf2f(h.w));
    *(ushort4*)(hi + (size_t)m * KP + kq * 4) = h;
    *(ushort4*)(lo + (size_t)m * KP + kq * 4) = l;
}

// ---- fp16 convert: dst[m][k] = fp16(src[m][k]) ----
__global__ __launch_bounds__(256) void cvt16_kernel(
        const float* __restrict__ src, int lda, int K4, int KP,
        unsigned short* __restrict__ dst, int total4) {
    int idx = blockIdx.x * 256 + threadIdx.x;
    if (idx >= total4) return;
    int m = idx / K4;
    int kq = idx - m * K4;
    float4 v = *(const float4*)(src + (size_t)m * lda + kq * 4);
    ushort4 h;
    h.x = f2h(v.x); h.y = f2h(v.y); h.z = f2h(v.z); h.w = f2h(v.w);
    *(ushort4*)(dst + (size_t)m * KP + kq * 4) = h;
}

// ---- LoRA K-extension columns (bf16 hi/lo), ncols cols from K ----
__global__ __launch_bounds__(256) void ext_kernel(
        const float* __restrict__ t16, int K, int KP, int ncols,
        unsigned short* __restrict__ hi, unsigned short* __restrict__ lo,
        int M) {
    int idx = blockIdx.x * 256 + threadIdx.x;
    if (idx >= M * ncols) return;
    int c = idx % ncols, m = idx / ncols;
    unsigned short hv = 0;
    if (c < 16) hv = f2bf(t16[(size_t)m * 16 + c]);
    hi[(size_t)m * KP + K + c] = hv;
    lo[(size_t)m * KP + K + c] = 0;
}

// ---- LoRA K-extension columns (fp16 single) ----
__global__ __launch_bounds__(256) void ext16_kernel(
        const float* __restrict__ t16, int K, int KP,
        unsigned short* __restrict__ dst, int M) {
    int idx = blockIdx.x * 256 + threadIdx.x;
    if (idx >= M * 32) return;
    int c = idx & 31, m = idx >> 5;
    unsigned short hv = 0;
    if (c < 16) hv = f2h(t16[(size_t)m * 16 + c]);
    dst[(size_t)m * KP + K + c] = hv;
}

// ---- fp16 single-pass MFMA GEMM, 2-phase dbuf ----
template<int EPI>
__global__ __launch_bounds__(256, 4) void mfma_gemm16(
        const unsigned short* __restrict__ Ag, const unsigned short* __restrict__ Wg,
        int KP, float* __restrict__ C, int ldc,
        const float* __restrict__ bias) {
    __shared__ __align__(16) short Ash[2][4][128][8];
    __shared__ __align__(16) short Wsh[2][4][128][8];
    const int tid = threadIdx.x;
    const int bn0 = blockIdx.x * 128, bm0 = blockIdx.y * 128;
    const int wave = tid >> 6, lane = tid & 63;
    const int wr = (wave >> 1) * 64, wc = (wave & 1) * 64;
    const int fr = lane & 15, fg = lane >> 4;
    const int KT = KP >> 5;
    const int srow = tid & 127, skg = tid >> 7;

    const unsigned short* pA = Ag + (size_t)(bm0 + srow) * KP + skg * 8;
    const unsigned short* pW = Wg + (size_t)(bn0 + srow) * KP + skg * 8;

    f32x4 acc[4][4];
    #pragma unroll
    for (int i = 0; i < 4; ++i)
        #pragma unroll
        for (int j = 0; j < 4; ++j) acc[i][j] = (f32x4){0.f, 0.f, 0.f, 0.f};

    auto stage = [&](int kt, int pb) {
        const int koff = kt * 32;
        gll16(pA + koff,      &Ash[pb][skg    ][srow][0]);
        gll16(pA + koff + 16, &Ash[pb][skg + 2][srow][0]);
        gll16(pW + koff,      &Wsh[pb][skg    ][srow][0]);
        gll16(pW + koff + 16, &Wsh[pb][skg + 2][srow][0]);
    };

    stage(0, 0);
    for (int kt = 0; kt < KT; ++kt) {
        const int cur = kt & 1;
        __syncthreads();
        if (kt + 1 < KT) stage(kt + 1, cur ^ 1);
        f16x8 a[4], w[4];
        #pragma unroll
        for (int i = 0; i < 4; ++i) {
            a[i] = *(const f16x8*)&Ash[cur][fg][wr + i * 16 + fr][0];
            w[i] = *(const f16x8*)&Wsh[cur][fg][wc + i * 16 + fr][0];
        }
        #pragma unroll
        for (int i = 0; i < 4; ++i)
            #pragma unroll
            for (int j = 0; j < 4; ++j)
                acc[i][j] = __builtin_amdgcn_mfma_f32_16x16x32_f16(a[i], w[j], acc[i][j], 0, 0, 0);
    }
    #pragma unroll
    for (int i = 0; i < 4; ++i) {
        #pragma unroll
        for (int j = 0; j < 4; ++j) {
            int n = bn0 + wc + j * 16 + fr;
            #pragma unroll
            for (int q = 0; q < 4; ++q) {
                int m = bm0 + wr + i * 16 + fg * 4 + q;
                float v = acc[i][j][q];
                if (EPI == 2) v = softplusf(v + bias[n]);
                C[(size_t)m * ldc + n] = v;
            }
        }
    }
}

// ---- hi/lo bf16 3-pass MFMA GEMM, 2-phase dbuf, optional split-K ----
// kchunk != 0: block z handles K range [z*kchunk, z*kchunk + kchunk) and
// writes its partial to C + z * (gridDim.y*128) * ldc.
template<int EPI>
__global__ __launch_bounds__(256, 2) void mfma_gemm(
        const unsigned short* __restrict__ Ahg, const unsigned short* __restrict__ Alg,
        const unsigned short* __restrict__ Whg, const unsigned short* __restrict__ Wlg,
        int KP, float* __restrict__ C, int ldc,
        const float* __restrict__ bias, int kchunk) {
    __shared__ __align__(16) short Ash[2][4][128][8];
    __shared__ __align__(16) short Asl[2][4][128][8];
    __shared__ __align__(16) short Wsh[2][4][128][8];
    __shared__ __align__(16) short Wsl[2][4][128][8];
    const int tid = threadIdx.x;
    const int bn0 = blockIdx.x * 128, bm0 = blockIdx.y * 128;
    const int wave = tid >> 6, lane = tid & 63;
    const int wr = (wave >> 1) * 64, wc = (wave & 1) * 64;
    const int fr = lane & 15, fg = lane >> 4;
    int koff0 = 0, KT;
    if (kchunk) {
        koff0 = blockIdx.z * kchunk;
        KT = kchunk >> 5;
        C += (size_t)blockIdx.z * gridDim.y * 128 * ldc;
    } else {
        KT = KP >> 5;
    }
    const int srow = tid & 127, skg = tid >> 7;

    const unsigned short* pAh = Ahg + (size_t)(bm0 + srow) * KP + koff0 + skg * 8;
    const unsigned short* pAl = Alg + (size_t)(bm0 + srow) * KP + koff0 + skg * 8;
    const unsigned short* pWh = Whg + (size_t)(bn0 + srow) * KP + koff0 + skg * 8;
    const unsigned short* pWl = Wlg + (size_t)(bn0 + srow) * KP + koff0 + skg * 8;

    f32x4 acc[4][4];
    #pragma unroll
    for (int i = 0; i < 4; ++i)
        #pragma unroll
        for (int j = 0; j < 4; ++j) acc[i][j] = (f32x4){0.f, 0.f, 0.f, 0.f};

    auto stage = [&](int kt, int pb) {
        const int koff = kt * 32;
        gll16(pAh + koff,      &Ash[pb][skg    ][srow][0]);
        gll16(pAh + koff + 16, &Ash[pb][skg + 2][srow][0]);
        gll16(pAl + koff,      &Asl[pb][skg    ][srow][0]);
        gll16(pAl + koff + 16, &Asl[pb][skg + 2][srow][0]);
        gll16(pWh + koff,      &Wsh[pb][skg    ][srow][0]);
        gll16(pWh + koff + 16, &Wsh[pb][skg + 2][srow][0]);
        gll16(pWl + koff,      &Wsl[pb][skg    ][srow][0]);
        gll16(pWl + koff + 16, &Wsl[pb][skg + 2][srow][0]);
    };

    stage(0, 0);
    for (int kt = 0; kt < KT; ++kt) {
        const int cur = kt & 1;
        __syncthreads();
        if (kt + 1 < KT) stage(kt + 1, cur ^ 1);
        s16x8 ah[4], al[4], wh[4], wl[4];
        #pragma unroll
        for (int i = 0; i < 4; ++i) {
            ah[i] = *(const s16x8*)&Ash[cur][fg][wr + i * 16 + fr][0];
            al[i] = *(const s16x8*)&Asl[cur][fg][wr + i * 16 + fr][0];
            wh[i] = *(const s16x8*)&Wsh[cur][fg][wc + i * 16 + fr][0];
            wl[i] = *(const s16x8*)&Wsl[cur][fg][wc + i * 16 + fr][0];
        }
        #pragma unroll
        for (int i = 0; i < 4; ++i)
            #pragma unroll
            for (int j = 0; j < 4; ++j) {
                acc[i][j] = __builtin_amdgcn_mfma_f32_16x16x32_bf16(ah[i], wh[j], acc[i][j], 0, 0, 0);
                acc[i][j] = __builtin_amdgcn_mfma_f32_16x16x32_bf16(ah[i], wl[j], acc[i][j], 0, 0, 0);
                acc[i][j] = __builtin_amdgcn_mfma_f32_16x16x32_bf16(al[i], wh[j], acc[i][j], 0, 0, 0);
            }
    }
    #pragma unroll
    for (int i = 0; i < 4; ++i) {
        #pragma unroll
        for (int j = 0; j < 4; ++j) {
            int n = bn0 + wc + j * 16 + fr;
            #pragma unroll
            for (int q = 0; q < 4; ++q) {
                int m = bm0 + wr + i * 16 + fg * 4 + q;
                float v = acc[i][j][q];
                if (EPI == 2) v = softplusf(v + bias[n]);
                C[(size_t)m * ldc + n] = v;
            }
        }
    }
}

// ---- out[i] = p[i] + p[total+i]  (split-K=2 reduce) ----
__global__ __launch_bounds__(256) void sk2_reduce_kernel(
        const float* __restrict__ p, float* __restrict__ out, int total) {
    int i = blockIdx.x * 256 + threadIdx.x;
    if (i < total) out[i] = p[i] + p[(size_t)total + i];
}

// ---- fp32 tiled GEMM (x_proj split-K; N=96) ----
__global__ __launch_bounds__(256) void gemm_f32_kernel(
        const float* __restrict__ A, int lda,
        const float* __restrict__ W, int ldw,
        float* __restrict__ C, int ldc,
        int M, int N, int K, int kchunk) {
    __shared__ float As[8][128];
    __shared__ float Bs[8][128];
    if (kchunk) {
        A += (size_t)blockIdx.z * kchunk;
        W += (size_t)blockIdx.z * kchunk;
        C += (size_t)blockIdx.z * M * ldc;
    }
    const int tid = threadIdx.x;
    const int tx = tid & 15, ty = tid >> 4;
    const int bn0 = blockIdx.x * 128, bm0 = blockIdx.y * 128;
    const int lrow = tid >> 1;
    const int lk   = (tid & 1) * 4;
    const int nk = K >> 3;

    float acc[8][8];
    #pragma unroll
    for (int i = 0; i < 8; ++i)
        #pragma unroll
        for (int j = 0; j < 8; ++j) acc[i][j] = 0.f;

    float4 av, wv;
    {
        av = *(const float4*)(A + (size_t)(bm0 + lrow) * lda + lk);
        int n = bn0 + lrow;
        wv = (n < N) ? *(const float4*)(W + (size_t)n * ldw + lk)
                     : make_float4(0.f, 0.f, 0.f, 0.f);
    }
    for (int kt = 0; kt < nk; ++kt) {
        __syncthreads();
        As[lk + 0][lrow] = av.x; As[lk + 1][lrow] = av.y;
        As[lk + 2][lrow] = av.z; As[lk + 3][lrow] = av.w;
        Bs[lk + 0][lrow] = wv.x; Bs[lk + 1][lrow] = wv.y;
        Bs[lk + 2][lrow] = wv.z; Bs[lk + 3][lrow] = wv.w;
        __syncthreads();
        int kt1 = kt + 1;
        if (kt1 < nk) {
            int n = bn0 + lrow;
            av = *(const float4*)(A + (size_t)(bm0 + lrow) * lda + (size_t)kt1 * 8 + lk);
            wv = (n < N) ? *(const float4*)(W + (size_t)n * ldw + (size_t)kt1 * 8 + lk)
                         : make_float4(0.f, 0.f, 0.f, 0.f);
        }
        #pragma unroll
        for (int k = 0; k < 8; ++k) {
            float a[8], b[8];
            #pragma unroll
            for (int i = 0; i < 8; ++i) a[i] = As[k][ty + 16 * i];
            #pragma unroll
            for (int j = 0; j < 8; ++j) b[j] = Bs[k][tx + 16 * j];
            #pragma unroll
            for (int i = 0; i < 8; ++i)
                #pragma unroll
                for (int j = 0; j < 8; ++j)
                    acc[i][j] = fmaf(a[i], b[j], acc[i][j]);
        }
    }
    #pragma unroll
    for (int i = 0; i < 8; ++i) {
        int m = bm0 + ty + 16 * i;
        #pragma unroll
        for (int j = 0; j < 8; ++j) {
            int n = bn0 + tx + 16 * j;
            if (n < N) C[(size_t)m * ldc + n] = acc[i][j];
        }
    }
}

// ---- reduce split-K partials (SKX-way, x_proj) ----
__global__ __launch_bounds__(256) void sk_reduce_kernel(
        const float* __restrict__ part, float* __restrict__ out, int total) {
    int i = blockIdx.x * 256 + threadIdx.x;
    if (i >= total) return;
    float s = 0.f;
    #pragma unroll
    for (int sk = 0; sk < SKX; ++sk) s += part[(size_t)sk * total + i];
    out[i] = s;
}

// ---- depthwise causal conv(4) + bias + SiLU ----
__global__ __launch_bounds__(256) void conv_silu_kernel(
        const float* __restrict__ xz, const float* __restrict__ cw,
        const float* __restrict__ cb, float* __restrict__ u) {
    int idx = blockIdx.x * 256 + threadIdx.x;
    int d  = idx & (D_INNER - 1);
    int bl = idx >> 11;
    int l  = bl & (SEQLEN - 1);
    const float* base = xz + (size_t)bl * 4096 + d;
    float4 w = *(const float4*)(cw + d * 4);
    float s = cb[d];
    if (l >= 3) s = fmaf(base[-3 * 4096], w.x, s);
    if (l >= 2) s = fmaf(base[-2 * 4096], w.y, s);
    if (l >= 1) s = fmaf(base[-1 * 4096], w.z, s);
    s = fmaf(base[0], w.w, s);
    u[idx] = s * __builtin_amdgcn_rcpf(1.f + __expf(-s));
}

// ================= chunk-parallel selective scan (per-thread h[16]) ========
__global__ __launch_bounds__(256) void scan_partA(
        const float* __restrict__ delta, const float* __restrict__ u,
        const float* __restrict__ xdbl, const float* __restrict__ A_log,
        float* __restrict__ hF, float* __restrict__ sumd) {
    const int tid = threadIdx.x;
    const int bx  = blockIdx.x;
    const int seg = bx >> 4;
    const int b   = (bx >> 3) & 1;
    const int d   = (bx & 7) * 256 + tid;
    const int t0  = seg * TSEG;
    float An2[16];
    #pragma unroll
    for (int q = 0; q < 4; ++q) {
        float4 a = *(const float4*)(A_log + d * 16 + q * 4);
        An2[q*4+0] = -__expf(a.x) * LOG2E;
        An2[q*4+1] = -__expf(a.y) * LOG2E;
        An2[q*4+2] = -__expf(a.z) * LOG2E;
        An2[q*4+3] = -__expf(a.w) * LOG2E;
    }
    const float* dl = delta + ((size_t)b * SEQLEN + t0) * D_INNER + d;
    const float* uu = u     + ((size_t)b * SEQLEN + t0) * D_INNER + d;
    const float* bc = xdbl  + ((size_t)b * SEQLEN + t0) * 96 + 64;
    float h[16];
    #pragma unroll
    for (int n = 0; n < 16; ++n) h[n] = 0.f;
    float sd = 0.f;
    float pdv[4], puv[4];
    #pragma unroll
    for (int j = 0; j < 4; ++j) {
        pdv[j] = dl[(size_t)j * D_INNER];
        puv[j] = uu[(size_t)j * D_INNER];
    }
    for (int t4 = 0; t4 < TSEG; t4 += 4) {
        #pragma unroll
        for (int j = 0; j < 4; ++j) {
            const float dv = pdv[j], uv = puv[j];
            if (t4 + 4 < TSEG) {
                pdv[j] = dl[(size_t)(t4 + 4 + j) * D_INNER];
                puv[j] = uu[(size_t)(t4 + 4 + j) * D_INNER];
            }
            const float* bct = bc + (size_t)(t4 + j) * 96;
            float4 B0 = *(const float4*)(bct);
            float4 B1 = *(const float4*)(bct + 4);
            float4 B2 = *(const float4*)(bct + 8);
            float4 B3 = *(const float4*)(bct + 12);
            float Bv[16] = {B0.x,B0.y,B0.z,B0.w, B1.x,B1.y,B1.z,B1.w,
                            B2.x,B2.y,B2.z,B2.w, B3.x,B3.y,B3.z,B3.w};
            const float dvuv = dv * uv;
            sd += dv;
            #pragma unroll
            for (int n = 0; n < 16; ++n)
                h[n] = fmaf(exp2f(dv * An2[n]), h[n], dvuv * Bv[n]);
        }
    }
    const size_t o = (size_t)seg * (BATCH * D_INNER) + (size_t)b * D_INNER + d;
    #pragma unroll
    for (int q = 0; q < 4; ++q)
        *(float4*)(hF + o * 16 + q * 4) =
            make_float4(h[q*4], h[q*4+1], h[q*4+2], h[q*4+3]);
    sumd[o] = sd;
}

__global__ __launch_bounds__(256) void scan_combine(
        const float* __restrict__ A_log, float* __restrict__ hFin,
        const float* __restrict__ sumd) {
    int idx = blockIdx.x * 256 + threadIdx.x;
    int n = idx & 15, row = idx >> 4;
    int d = row & (D_INNER - 1);
    float An = -__expf(A_log[d * 16 + n]);
    float f[NSEG], p[NSEG];
    #pragma unroll
    for (int s = 0; s < NSEG; ++s) {
        size_t o = (size_t)s * (BATCH * D_INNER) + row;
        f[s] = hFin[o * 16 + n];
        p[s] = __expf(An * sumd[o]);
    }
    float h = 0.f;
    #pragma unroll
    for (int s = 0; s < NSEG; ++s) {
        size_t o = (size_t)s * (BATCH * D_INNER) + row;
        hFin[o * 16 + n] = h;
        h = fmaf(p[s], h, f[s]);
    }
}

__global__ __launch_bounds__(256) void scan_partB(
        const float* delta, const float* __restrict__ u,
        const float* __restrict__ xdbl, const float* __restrict__ xz,
        const float* __restrict__ A_log, const float* __restrict__ Dp,
        const float* __restrict__ hin, float* yg) {
    const int tid = threadIdx.x;
    const int bx  = blockIdx.x;
    const int seg = bx >> 4;
    const int b   = (bx >> 3) & 1;
    const int d   = (bx & 7) * 256 + tid;
    const int t0  = seg * TSEG;
    float An2[16];
    #pragma unroll
    for (int q = 0; q < 4; ++q) {
        float4 a = *(const float4*)(A_log + d * 16 + q * 4);
        An2[q*4+0] = -__expf(a.x) * LOG2E;
        An2[q*4+1] = -__expf(a.y) * LOG2E;
        An2[q*4+2] = -__expf(a.z) * LOG2E;
        An2[q*4+3] = -__expf(a.w) * LOG2E;
    }
    const float Dd = Dp[d];
    const float* dl = delta + ((size_t)b * SEQLEN + t0) * D_INNER + d;
    const float* uu = u     + ((size_t)b * SEQLEN + t0) * D_INNER + d;
    const float* bc = xdbl  + ((size_t)b * SEQLEN + t0) * 96 + 64;
    const float* zz = xz    + ((size_t)b * SEQLEN + t0) * 4096 + D_INNER + d;
    float* yo = yg + ((size_t)b * SEQLEN + t0) * D_INNER + d;
    const size_t o = (size_t)seg * (BATCH * D_INNER) + (size_t)b * D_INNER + d;
    float h[16];
    #pragma unroll
    for (int q = 0; q < 4; ++q) {
        float4 hv = *(const float4*)(hin + o * 16 + q * 4);
        h[q*4] = hv.x; h[q*4+1] = hv.y; h[q*4+2] = hv.z; h[q*4+3] = hv.w;
    }
    float pdv[4], puv[4], pzv[4];
    #pragma unroll
    for (int j = 0; j < 4; ++j) {
        pdv[j] = dl[(size_t)j * D_INNER];
        puv[j] = uu[(size_t)j * D_INNER];
        pzv[j] = zz[(size_t)j * 4096];
    }
    for (int t4 = 0; t4 < TSEG; t4 += 4) {
        #pragma unroll
        for (int j = 0; j < 4; ++j) {
            const float dv = pdv[j], uv = puv[j], zv = pzv[j];
            if (t4 + 4 < TSEG) {
                pdv[j] = dl[(size_t)(t4 + 4 + j) * D_INNER];
                puv[j] = uu[(size_t)(t4 + 4 + j) * D_INNER];
                pzv[j] = zz[(size_t)(t4 + 4 + j) * 4096];
            }
            const float* bct = bc + (size_t)(t4 + j) * 96;
            float4 B0 = *(const float4*)(bct);
            float4 B1 = *(const float4*)(bct + 4);
            float4 B2 = *(const float4*)(bct + 8);
            float4 B3 = *(const float4*)(bct + 12);
            float4 C0 = *(const float4*)(bct + 16);
            float4 C1 = *(const float4*)(bct + 20);
            float4 C2 = *(const float4*)(bct + 24);
            float4 C3 = *(const float4*)(bct + 28);
            float Bv[16] = {B0.x,B0.y,B0.z,B0.w, B1.x,B1.y,B1.z,B1.w,
                            B2.x,B2.y,B2.z,B2.w, B3.x,B3.y,B3.z,B3.w};
            float Cv[16] = {C0.x,C0.y,C0.z,C0.w, C1.x,C1.y,C1.z,C1.w,
                            C2.x,C2.y,C2.z,C2.w, C3.x,C3.y,C3.z,C3.w};
            const float dvuv = dv * uv;
            #pragma unroll
            for (int n = 0; n < 16; ++n)
                h[n] = fmaf(exp2f(dv * An2[n]), h[n], dvuv * Bv[n]);
            float acc[4] = {0.f, 0.f, 0.f, 0.f};
            #pragma unroll
            for (int n = 0; n < 16; ++n)
                acc[n & 3] = fmaf(h[n], Cv[n], acc[n & 3]);
            float yv = fmaf(uv, Dd, (acc[0] + acc[1]) + (acc[2] + acc[3]));
            float sig = zv * __builtin_amdgcn_rcpf(1.f + __expf(-zv));
            yo[(size_t)(t4 + j) * D_INNER] = yv * sig;
        }
    }
}

extern "C" void kernel_launch(void* const* d_in, const int* in_sizes, int n_in,
                              void* d_out, int out_size, void* d_ws, size_t ws_size,
                              hipStream_t stream) {
    const float* x        = (const float*)d_in[0];
    const float* w_in     = (const float*)d_in[1];
    const float* lA_in    = (const float*)d_in[2];
    const float* lB_in    = (const float*)d_in[3];
    const float* mask_in  = (const float*)d_in[4];
    const float* conv_w   = (const float*)d_in[5];
    const float* conv_b   = (const float*)d_in[6];
    const float* w_xp     = (const float*)d_in[7];
    const float* w_dt     = (const float*)d_in[8];
    const float* b_dt     = (const float*)d_in[9];
    const float* A_log    = (const float*)d_in[10];
    const float* Dp       = (const float*)d_in[11];
    const float* w_out    = (const float*)d_in[12];
    const float* lA_out   = (const float*)d_in[13];
    const float* lB_out   = (const float*)d_in[14];
    const float* mask_out = (const float*)d_in[15];

    // f32 workspace layout
    float* ws    = (float*)d_ws;
    float* xz    = ws;                              // [BL,4096]
    float* u     = xz    + (size_t)BL * 4096;       // [BL,2048]
    float* delta = u     + (size_t)BL * D_INNER;    // [BL,2048] (also yg; also out_proj partials)
    float* xdbl  = delta + (size_t)BL * D_INNER;    // [BL,96]
    float* t16   = xdbl  + (size_t)BL * 96;         // [BL,16]
    float* lbin  = t16   + (size_t)BL * 16;         // [4096,16]
    float* lbout = lbin  + (size_t)4096 * 16;       // [1024,16]

    // fp16 arenas for in_proj in dead u region
    unsigned short* Ah16_in = (unsigned short*)u;                 // [4096][1056]
    unsigned short* Wh16_in = Ah16_in + (size_t)4096 * 1056;      // [4096][1056]

    // fp16 arenas for dt_proj in d_out scratch
    unsigned short* Ah16_dt = (unsigned short*)d_out;             // [4096][64]
    unsigned short* Wh16_dt = Ah16_dt + (size_t)4096 * 64;        // [2048][64]

    // bf16 hi/lo arenas for out_proj in dead xz region; KP=2112 (2 x 1056)
    const int KP_OUT = 2112, KH_OUT = 1056;
    const size_t AS_OUT = (size_t)4096 * KP_OUT, WS_OUT = (size_t)1024 * KP_OUT;
    unsigned short* Ahi_out = (unsigned short*)xz;
    unsigned short* Alo_out = Ahi_out + AS_OUT;
    unsigned short* Whi_out = Alo_out + AS_OUT;
    unsigned short* Wlo_out = Whi_out + WS_OUT;
    // arenas end at 10240*2112*2 = 43.25 MB < 67.1 MB (xz region) ✓

    // d_out f32 scratch (pre-final uses)
    float* outf    = (float*)d_out;
    float* xp_part = outf;                                  // [SKX][BL*96]
    float* hFin    = outf;                                  // [NSEG][4096][16]
    float* sumd    = hFin + (size_t)NSEG * BATCH * D_INNER * 16;

    // 1) LoRA premultiply + t16_in
    premul_kernel<<<(4096 * 16 + 255) / 256, 256, 0, stream>>>(lB_in, mask_in, lbin, 4096 * 16);
    premul_kernel<<<(1024 * 16 + 255) / 256, 256, 0, stream>>>(lB_out, mask_out, lbout, 1024 * 16);
    lora_t_kernel<<<BL, 256, 0, stream>>>(x, D_MODEL, lA_in, D_MODEL, t16);
    // 2) fp16 conversions for in_proj (K=1024, KP=1056 incl. LoRA ext)
    cvt16_kernel<<<4096, 256, 0, stream>>>(x,    1024, 256, 1056, Ah16_in, 4096 * 256);
    cvt16_kernel<<<4096, 256, 0, stream>>>(w_in, 1024, 256, 1056, Wh16_in, 4096 * 256);
    ext16_kernel<<<512, 256, 0, stream>>>(t16,  1024, 1056, Ah16_in, 4096);
    ext16_kernel<<<512, 256, 0, stream>>>(lbin, 1024, 1056, Wh16_in, 4096);
    // 3) in_proj fp16 MFMA GEMM -> xz
    mfma_gemm16<0><<<dim3(32, 32), 256, 0, stream>>>(
        Ah16_in, Wh16_in, 1056, xz, 4096, nullptr);
    // 4) u = silu(conv(xs) + b)
    conv_silu_kernel<<<(BL * D_INNER) / 256, 256, 0, stream>>>(xz, conv_w, conv_b, u);
    // 5) x_proj split-K fp32 -> xdbl
    gemm_f32_kernel<<<dim3(1, BL / 128, SKX), 256, 0, stream>>>(
        u, D_INNER, w_xp, D_INNER, xp_part, 96, BL, 96, KCH, KCH);
    sk_reduce_kernel<<<(BL * 96 + 255) / 256, 256, 0, stream>>>(xp_part, xdbl, BL * 96);
    // 6) dt_proj fp16 MFMA (K=64) -> delta = softplus(. + b_dt)
    cvt16_kernel<<<(4096 * 16 + 255) / 256, 256, 0, stream>>>(xdbl, 96, 16, 64, Ah16_dt, 4096 * 16);
    cvt16_kernel<<<(2048 * 16 + 255) / 256, 256, 0, stream>>>(w_dt, 64, 16, 64, Wh16_dt, 2048 * 16);
    mfma_gemm16<2><<<dim3(16, 32), 256, 0, stream>>>(
        Ah16_dt, Wh16_dt, 64, delta, 2048, b_dt);
    // 7) chunk-parallel selective scan (+ gating); yg aliases delta
    scan_partA<<<NSEG * BATCH * 8, 256, 0, stream>>>(delta, u, xdbl, A_log, hFin, sumd);
    scan_combine<<<(BATCH * D_INNER * 16) / 256, 256, 0, stream>>>(A_log, hFin, sumd);
    scan_partB<<<NSEG * BATCH * 8, 256, 0, stream>>>(delta, u, xdbl, xz, A_log, Dp, hFin, delta);
    // 8) out_proj: t16_out + bf16 hi/lo conversions (K=2048, KP=2112)
    lora_t_kernel<<<BL, 256, 0, stream>>>(delta, D_INNER, lA_out, D_INNER, t16);
    hilo_kernel<<<8192, 256, 0, stream>>>(delta, 2048, 512, KP_OUT, Ahi_out, Alo_out, 4096 * 512);
    hilo_kernel<<<2048, 256, 0, stream>>>(w_out, 2048, 512, KP_OUT, Whi_out, Wlo_out, 1024 * 512);
    ext_kernel<<<(4096 * 64 + 255) / 256, 256, 0, stream>>>(t16,   2048, KP_OUT, 64, Ahi_out, Alo_out, 4096);
    ext_kernel<<<(1024 * 64 + 255) / 256, 256, 0, stream>>>(lbout, 2048, KP_OUT, 64, Whi_out, Wlo_out, 1024);
    // 9) out_proj split-K=2 MFMA -> partials in dead delta region, then reduce
    float* P = delta;   // [2][4096*1024] f32 — delta/yg dead after hilo+lora_t
    mfma_gemm<0><<<dim3(8, 32, 2), 256, 0, stream>>>(
        Ahi_out, Alo_out, Whi_out, Wlo_out, KP_OUT, P, 1024, nullptr, KH_OUT);
    sk2_reduce_kernel<<<(4096 * 1024) / 256, 256, 0, stream>>>(P, (float*)d_out, 4096 * 1024);
}

// Round 10
// 442.782 us; speedup vs baseline: 1.6007x; 1.1931x over previous
//
#include <hip/hip_runtime.h>
#include <hip/hip_bf16.h>
#include <hip/hip_fp16.h>
#include <cstdint>
#include <cstddef>

// Problem constants (from reference)
#define D_MODEL 1024
#define D_INNER 2048
#define NSTATE  16
#define DTRANK  64
#define BATCH   2
#define SEQLEN  2048
#define BL      (BATCH*SEQLEN)   // 4096 tokens
#define NSEG    32
#define TSEG    (SEQLEN/NSEG)    // 64
#define SKX     8                // split-K factor for x_proj
#define KCH     (D_INNER/SKX)    // 256
#define LOG2E   1.4426950408889634f

typedef __attribute__((ext_vector_type(8))) _Float16 f16x8;
typedef __attribute__((ext_vector_type(4))) float f32x4;

__device__ __forceinline__ float softplusf(float x) {
    return fmaxf(x, 0.f) + log1pf(expf(-fabsf(x)));
}
__device__ __forceinline__ unsigned short f2h(float x) {
    __half h = __float2half(x);
    return *(unsigned short*)&h;
}
// async global->LDS, 16B per lane (dest must be linear: base + lane*16)
__device__ __forceinline__ void gll16(const void* g, void* l) {
    __builtin_amdgcn_global_load_lds(
        (const __attribute__((address_space(1))) void*)g,
        (__attribute__((address_space(3))) void*)l, 16, 0, 0);
}

// ---- lbp[n,r] = lora_B[n,r] * mask[n] * 2.0 ----
__global__ __launch_bounds__(256) void premul_kernel(
        const float* __restrict__ lb, const float* __restrict__ mask,
        float* __restrict__ out, int total) {
    int i = blockIdx.x * 256 + threadIdx.x;
    if (i < total) out[i] = lb[i] * mask[i >> 4] * 2.0f;
}

// ---- T[m,r] = sum_k X[m,k] * LA[r,k]   (r < 16) ----
__global__ __launch_bounds__(256) void lora_t_kernel(
        const float* __restrict__ X, int ldx,
        const float* __restrict__ LA, int K,
        float* __restrict__ T) {
    int m = blockIdx.x;
    int r = threadIdx.x >> 4;
    int l = threadIdx.x & 15;
    const float* xrow = X + (size_t)m * ldx;
    const float* arow = LA + (size_t)r * K;
    float s = 0.f;
    for (int k = 4 * l; k < K; k += 64) {
        float4 xv = *(const float4*)(xrow + k);
        float4 av = *(const float4*)(arow + k);
        s += xv.x * av.x + xv.y * av.y + xv.z * av.z + xv.w * av.w;
    }
    #pragma unroll
    for (int o = 8; o; o >>= 1) s += __shfl_xor(s, o, 16);
    if (l == 0) T[(size_t)m * 16 + r] = s;
}

// ---- fp16 convert: dst[m][k] = fp16(src[m][k]) ----
__global__ __launch_bounds__(256) void cvt16_kernel(
        const float* __restrict__ src, int lda, int K4, int KP,
        unsigned short* __restrict__ dst, int total4) {
    int idx = blockIdx.x * 256 + threadIdx.x;
    if (idx >= total4) return;
    int m = idx / K4;
    int kq = idx - m * K4;
    float4 v = *(const float4*)(src + (size_t)m * lda + kq * 4);
    ushort4 h;
    h.x = f2h(v.x); h.y = f2h(v.y); h.z = f2h(v.z); h.w = f2h(v.w);
    *(ushort4*)(dst + (size_t)m * KP + kq * 4) = h;
}

// ---- fp16 convert with row padding: rows >= Msrc write zeros ----
__global__ __launch_bounds__(256) void cvtpad16_kernel(
        const float* __restrict__ src, int Msrc, int K4,
        unsigned short* __restrict__ dst, int total4) {
    int idx = blockIdx.x * 256 + threadIdx.x;
    if (idx >= total4) return;
    int m = idx / K4;
    int kq = idx - m * K4;
    ushort4 h = {0, 0, 0, 0};
    if (m < Msrc) {
        float4 v = *(const float4*)(src + (size_t)m * (K4 * 4) + kq * 4);
        h.x = f2h(v.x); h.y = f2h(v.y); h.z = f2h(v.z); h.w = f2h(v.w);
    }
    *(ushort4*)(dst + (size_t)m * (K4 * 4) + kq * 4) = h;
}

// ---- LoRA K-extension columns (fp16): cols [K,K+16)=t16, [K+16,K+ncols)=0 ----
__global__ __launch_bounds__(256) void ext16_kernel(
        const float* __restrict__ t16, int K, int KP, int ncols,
        unsigned short* __restrict__ dst, int M) {
    int idx = blockIdx.x * 256 + threadIdx.x;
    if (idx >= M * ncols) return;
    int c = idx % ncols, m = idx / ncols;
    unsigned short hv = 0;
    if (c < 16) hv = f2h(t16[(size_t)m * 16 + c]);
    dst[(size_t)m * KP + K + c] = hv;
}

// ---- fp16 single-pass MFMA GEMM, 2-phase dbuf, optional split-K + N bound --
// kchunk != 0: block z handles K range [z*kchunk, ...); partial written to
// C + z * (gridDim.y*128) * ldc.
template<int EPI>
__global__ __launch_bounds__(256, 4) void mfma_gemm16(
        const unsigned short* __restrict__ Ag, const unsigned short* __restrict__ Wg,
        int KP, float* __restrict__ C, int ldc,
        const float* __restrict__ bias, int Nbound, int kchunk) {
    __shared__ __align__(16) short Ash[2][4][128][8];
    __shared__ __align__(16) short Wsh[2][4][128][8];
    const int tid = threadIdx.x;
    const int bn0 = blockIdx.x * 128, bm0 = blockIdx.y * 128;
    const int wave = tid >> 6, lane = tid & 63;
    const int wr = (wave >> 1) * 64, wc = (wave & 1) * 64;
    const int fr = lane & 15, fg = lane >> 4;
    int koff0 = 0, KT;
    if (kchunk) {
        koff0 = blockIdx.z * kchunk;
        KT = kchunk >> 5;
        C += (size_t)blockIdx.z * gridDim.y * 128 * ldc;
    } else {
        KT = KP >> 5;
    }
    const int srow = tid & 127, skg = tid >> 7;

    const unsigned short* pA = Ag + (size_t)(bm0 + srow) * KP + koff0 + skg * 8;
    const unsigned short* pW = Wg + (size_t)(bn0 + srow) * KP + koff0 + skg * 8;

    f32x4 acc[4][4];
    #pragma unroll
    for (int i = 0; i < 4; ++i)
        #pragma unroll
        for (int j = 0; j < 4; ++j) acc[i][j] = (f32x4){0.f, 0.f, 0.f, 0.f};

    auto stage = [&](int kt, int pb) {
        const int koff = kt * 32;
        gll16(pA + koff,      &Ash[pb][skg    ][srow][0]);
        gll16(pA + koff + 16, &Ash[pb][skg + 2][srow][0]);
        gll16(pW + koff,      &Wsh[pb][skg    ][srow][0]);
        gll16(pW + koff + 16, &Wsh[pb][skg + 2][srow][0]);
    };

    stage(0, 0);
    for (int kt = 0; kt < KT; ++kt) {
        const int cur = kt & 1;
        __syncthreads();   // drains vmcnt(0): buf[cur] staged; prev reads done
        if (kt + 1 < KT) stage(kt + 1, cur ^ 1);
        f16x8 a[4], w[4];
        #pragma unroll
        for (int i = 0; i < 4; ++i) {
            a[i] = *(const f16x8*)&Ash[cur][fg][wr + i * 16 + fr][0];
            w[i] = *(const f16x8*)&Wsh[cur][fg][wc + i * 16 + fr][0];
        }
        #pragma unroll
        for (int i = 0; i < 4; ++i)
            #pragma unroll
            for (int j = 0; j < 4; ++j)
                acc[i][j] = __builtin_amdgcn_mfma_f32_16x16x32_f16(a[i], w[j], acc[i][j], 0, 0, 0);
    }
    // C/D layout: col = lane&15, row = (lane>>4)*4 + q
    #pragma unroll
    for (int i = 0; i < 4; ++i) {
        #pragma unroll
        for (int j = 0; j < 4; ++j) {
            int n = bn0 + wc + j * 16 + fr;
            if (n < Nbound) {
                #pragma unroll
                for (int q = 0; q < 4; ++q) {
                    int m = bm0 + wr + i * 16 + fg * 4 + q;
                    float v = acc[i][j][q];
                    if (EPI == 2) v = softplusf(v + bias[n]);
                    C[(size_t)m * ldc + n] = v;
                }
            }
        }
    }
}

// ---- out[i] = p[i] + p[total+i]  (split-K=2 reduce) ----
__global__ __launch_bounds__(256) void sk2_reduce_kernel(
        const float* __restrict__ p, float* __restrict__ out, int total) {
    int i = blockIdx.x * 256 + threadIdx.x;
    if (i < total) out[i] = p[i] + p[(size_t)total + i];
}

// ---- reduce split-K partials (SKX-way, x_proj) ----
__global__ __launch_bounds__(256) void sk_reduce_kernel(
        const float* __restrict__ part, float* __restrict__ out, int total) {
    int i = blockIdx.x * 256 + threadIdx.x;
    if (i >= total) return;
    float s = 0.f;
    #pragma unroll
    for (int sk = 0; sk < SKX; ++sk) s += part[(size_t)sk * total + i];
    out[i] = s;
}

// ---- depthwise causal conv(4) + bias + SiLU; emits f32 u and fp16 u16 ----
__global__ __launch_bounds__(256) void conv_silu_kernel(
        const float* __restrict__ xz, const float* __restrict__ cw,
        const float* __restrict__ cb, float* __restrict__ u,
        unsigned short* __restrict__ u16) {
    int idx = blockIdx.x * 256 + threadIdx.x;
    int d  = idx & (D_INNER - 1);
    int bl = idx >> 11;
    int l  = bl & (SEQLEN - 1);
    const float* base = xz + (size_t)bl * 4096 + d;
    float4 w = *(const float4*)(cw + d * 4);
    float s = cb[d];
    if (l >= 3) s = fmaf(base[-3 * 4096], w.x, s);
    if (l >= 2) s = fmaf(base[-2 * 4096], w.y, s);
    if (l >= 1) s = fmaf(base[-1 * 4096], w.z, s);
    s = fmaf(base[0], w.w, s);
    float r = s * __builtin_amdgcn_rcpf(1.f + __expf(-s));
    u[idx] = r;
    u16[idx] = f2h(r);
}

// ================= chunk-parallel selective scan (per-thread h[16]) ========
__global__ __launch_bounds__(256) void scan_partA(
        const float* __restrict__ delta, const float* __restrict__ u,
        const float* __restrict__ xdbl, const float* __restrict__ A_log,
        float* __restrict__ hF, float* __restrict__ sumd) {
    const int tid = threadIdx.x;
    const int bx  = blockIdx.x;
    const int seg = bx >> 4;
    const int b   = (bx >> 3) & 1;
    const int d   = (bx & 7) * 256 + tid;
    const int t0  = seg * TSEG;
    float An2[16];
    #pragma unroll
    for (int q = 0; q < 4; ++q) {
        float4 a = *(const float4*)(A_log + d * 16 + q * 4);
        An2[q*4+0] = -__expf(a.x) * LOG2E;
        An2[q*4+1] = -__expf(a.y) * LOG2E;
        An2[q*4+2] = -__expf(a.z) * LOG2E;
        An2[q*4+3] = -__expf(a.w) * LOG2E;
    }
    const float* dl = delta + ((size_t)b * SEQLEN + t0) * D_INNER + d;
    const float* uu = u     + ((size_t)b * SEQLEN + t0) * D_INNER + d;
    const float* bc = xdbl  + ((size_t)b * SEQLEN + t0) * 96 + 64;
    float h[16];
    #pragma unroll
    for (int n = 0; n < 16; ++n) h[n] = 0.f;
    float sd = 0.f;
    float pdv[4], puv[4];
    #pragma unroll
    for (int j = 0; j < 4; ++j) {
        pdv[j] = dl[(size_t)j * D_INNER];
        puv[j] = uu[(size_t)j * D_INNER];
    }
    for (int t4 = 0; t4 < TSEG; t4 += 4) {
        #pragma unroll
        for (int j = 0; j < 4; ++j) {
            const float dv = pdv[j], uv = puv[j];
            if (t4 + 4 < TSEG) {
                pdv[j] = dl[(size_t)(t4 + 4 + j) * D_INNER];
                puv[j] = uu[(size_t)(t4 + 4 + j) * D_INNER];
            }
            const float* bct = bc + (size_t)(t4 + j) * 96;
            float4 B0 = *(const float4*)(bct);
            float4 B1 = *(const float4*)(bct + 4);
            float4 B2 = *(const float4*)(bct + 8);
            float4 B3 = *(const float4*)(bct + 12);
            float Bv[16] = {B0.x,B0.y,B0.z,B0.w, B1.x,B1.y,B1.z,B1.w,
                            B2.x,B2.y,B2.z,B2.w, B3.x,B3.y,B3.z,B3.w};
            const float dvuv = dv * uv;
            sd += dv;
            #pragma unroll
            for (int n = 0; n < 16; ++n)
                h[n] = fmaf(exp2f(dv * An2[n]), h[n], dvuv * Bv[n]);
        }
    }
    const size_t o = (size_t)seg * (BATCH * D_INNER) + (size_t)b * D_INNER + d;
    #pragma unroll
    for (int q = 0; q < 4; ++q)
        *(float4*)(hF + o * 16 + q * 4) =
            make_float4(h[q*4], h[q*4+1], h[q*4+2], h[q*4+3]);
    sumd[o] = sd;
}

__global__ __launch_bounds__(256) void scan_combine(
        const float* __restrict__ A_log, float* __restrict__ hFin,
        const float* __restrict__ sumd) {
    int idx = blockIdx.x * 256 + threadIdx.x;
    int n = idx & 15, row = idx >> 4;
    int d = row & (D_INNER - 1);
    float An = -__expf(A_log[d * 16 + n]);
    float f[NSEG], p[NSEG];
    #pragma unroll
    for (int s = 0; s < NSEG; ++s) {
        size_t o = (size_t)s * (BATCH * D_INNER) + row;
        f[s] = hFin[o * 16 + n];
        p[s] = __expf(An * sumd[o]);
    }
    float h = 0.f;
    #pragma unroll
    for (int s = 0; s < NSEG; ++s) {
        size_t o = (size_t)s * (BATCH * D_INNER) + row;
        hFin[o * 16 + n] = h;
        h = fmaf(p[s], h, f[s]);
    }
}

__global__ __launch_bounds__(256) void scan_partB(
        const float* delta, const float* __restrict__ u,
        const float* __restrict__ xdbl, const float* __restrict__ xz,
        const float* __restrict__ A_log, const float* __restrict__ Dp,
        const float* __restrict__ hin, float* yg) {
    const int tid = threadIdx.x;
    const int bx  = blockIdx.x;
    const int seg = bx >> 4;
    const int b   = (bx >> 3) & 1;
    const int d   = (bx & 7) * 256 + tid;
    const int t0  = seg * TSEG;
    float An2[16];
    #pragma unroll
    for (int q = 0; q < 4; ++q) {
        float4 a = *(const float4*)(A_log + d * 16 + q * 4);
        An2[q*4+0] = -__expf(a.x) * LOG2E;
        An2[q*4+1] = -__expf(a.y) * LOG2E;
        An2[q*4+2] = -__expf(a.z) * LOG2E;
        An2[q*4+3] = -__expf(a.w) * LOG2E;
    }
    const float Dd = Dp[d];
    const float* dl = delta + ((size_t)b * SEQLEN + t0) * D_INNER + d;
    const float* uu = u     + ((size_t)b * SEQLEN + t0) * D_INNER + d;
    const float* bc = xdbl  + ((size_t)b * SEQLEN + t0) * 96 + 64;
    const float* zz = xz    + ((size_t)b * SEQLEN + t0) * 4096 + D_INNER + d;
    float* yo = yg + ((size_t)b * SEQLEN + t0) * D_INNER + d;
    const size_t o = (size_t)seg * (BATCH * D_INNER) + (size_t)b * D_INNER + d;
    float h[16];
    #pragma unroll
    for (int q = 0; q < 4; ++q) {
        float4 hv = *(const float4*)(hin + o * 16 + q * 4);
        h[q*4] = hv.x; h[q*4+1] = hv.y; h[q*4+2] = hv.z; h[q*4+3] = hv.w;
    }
    float pdv[4], puv[4], pzv[4];
    #pragma unroll
    for (int j = 0; j < 4; ++j) {
        pdv[j] = dl[(size_t)j * D_INNER];
        puv[j] = uu[(size_t)j * D_INNER];
        pzv[j] = zz[(size_t)j * 4096];
    }
    for (int t4 = 0; t4 < TSEG; t4 += 4) {
        #pragma unroll
        for (int j = 0; j < 4; ++j) {
            const float dv = pdv[j], uv = puv[j], zv = pzv[j];
            if (t4 + 4 < TSEG) {
                pdv[j] = dl[(size_t)(t4 + 4 + j) * D_INNER];
                puv[j] = uu[(size_t)(t4 + 4 + j) * D_INNER];
                pzv[j] = zz[(size_t)(t4 + 4 + j) * 4096];
            }
            const float* bct = bc + (size_t)(t4 + j) * 96;
            float4 B0 = *(const float4*)(bct);
            float4 B1 = *(const float4*)(bct + 4);
            float4 B2 = *(const float4*)(bct + 8);
            float4 B3 = *(const float4*)(bct + 12);
            float4 C0 = *(const float4*)(bct + 16);
            float4 C1 = *(const float4*)(bct + 20);
            float4 C2 = *(const float4*)(bct + 24);
            float4 C3 = *(const float4*)(bct + 28);
            float Bv[16] = {B0.x,B0.y,B0.z,B0.w, B1.x,B1.y,B1.z,B1.w,
                            B2.x,B2.y,B2.z,B2.w, B3.x,B3.y,B3.z,B3.w};
            float Cv[16] = {C0.x,C0.y,C0.z,C0.w, C1.x,C1.y,C1.z,C1.w,
                            C2.x,C2.y,C2.z,C2.w, C3.x,C3.y,C3.z,C3.w};
            const float dvuv = dv * uv;
            #pragma unroll
            for (int n = 0; n < 16; ++n)
                h[n] = fmaf(exp2f(dv * An2[n]), h[n], dvuv * Bv[n]);
            float acc[4] = {0.f, 0.f, 0.f, 0.f};
            #pragma unroll
            for (int n = 0; n < 16; ++n)
                acc[n & 3] = fmaf(h[n], Cv[n], acc[n & 3]);
            float yv = fmaf(uv, Dd, (acc[0] + acc[1]) + (acc[2] + acc[3]));
            float sig = zv * __builtin_amdgcn_rcpf(1.f + __expf(-zv));
            yo[(size_t)(t4 + j) * D_INNER] = yv * sig;
        }
    }
}

extern "C" void kernel_launch(void* const* d_in, const int* in_sizes, int n_in,
                              void* d_out, int out_size, void* d_ws, size_t ws_size,
                              hipStream_t stream) {
    const float* x        = (const float*)d_in[0];
    const float* w_in     = (const float*)d_in[1];
    const float* lA_in    = (const float*)d_in[2];
    const float* lB_in    = (const float*)d_in[3];
    const float* mask_in  = (const float*)d_in[4];
    const float* conv_w   = (const float*)d_in[5];
    const float* conv_b   = (const float*)d_in[6];
    const float* w_xp     = (const float*)d_in[7];
    const float* w_dt     = (const float*)d_in[8];
    const float* b_dt     = (const float*)d_in[9];
    const float* A_log    = (const float*)d_in[10];
    const float* Dp       = (const float*)d_in[11];
    const float* w_out    = (const float*)d_in[12];
    const float* lA_out   = (const float*)d_in[13];
    const float* lB_out   = (const float*)d_in[14];
    const float* mask_out = (const float*)d_in[15];

    // f32 workspace layout
    float* ws    = (float*)d_ws;
    float* xz    = ws;                              // [BL,4096]
    float* u     = xz    + (size_t)BL * 4096;       // [BL,2048]
    float* delta = u     + (size_t)BL * D_INNER;    // [BL,2048] (delta/yg; u16; out partials)
    float* xdbl  = delta + (size_t)BL * D_INNER;    // [BL,96]
    float* t16   = xdbl  + (size_t)BL * 96;         // [BL,16]
    float* lbin  = t16   + (size_t)BL * 16;         // [4096,16]
    float* lbout = lbin  + (size_t)4096 * 16;       // [1024,16]

    // fp16 arenas for in_proj in dead u region
    unsigned short* A16_in = (unsigned short*)u;                 // [4096][1056]
    unsigned short* W16_in = A16_in + (size_t)4096 * 1056;       // [4096][1056]

    // u16 (x_proj A operand) in delta region while delta is dead
    unsigned short* u16 = (unsigned short*)delta;                // [4096][2048]

    // fp16 arenas for out_proj in dead xz region; KP=2112 (2 x 1056)
    const int KP_OUT = 2112, KH_OUT = 1056;
    unsigned short* A16_out = (unsigned short*)xz;               // [4096][2112]
    unsigned short* W16_out = A16_out + (size_t)4096 * KP_OUT;   // [1024][2112]

    // d_out f32 scratch (pre-final uses)
    float* outf    = (float*)d_out;
    float* xp_part = outf;                                   // [SKX][BL*96] = 12.6MB
    unsigned short* W16_xp = (unsigned short*)(outf + (size_t)SKX * BL * 96); // [128][2048]
    unsigned short* A16_dt = (unsigned short*)d_out;             // [4096][64] (after xp consumed)
    unsigned short* W16_dt = A16_dt + (size_t)4096 * 64;         // [2048][64]
    float* hFin    = outf;                                   // [NSEG][4096][16] (after dt consumed)
    float* sumd    = hFin + (size_t)NSEG * BATCH * D_INNER * 16;

    // 1) LoRA premultiply + t16_in
    premul_kernel<<<(4096 * 16 + 255) / 256, 256, 0, stream>>>(lB_in, mask_in, lbin, 4096 * 16);
    premul_kernel<<<(1024 * 16 + 255) / 256, 256, 0, stream>>>(lB_out, mask_out, lbout, 1024 * 16);
    lora_t_kernel<<<BL, 256, 0, stream>>>(x, D_MODEL, lA_in, D_MODEL, t16);
    // 2) fp16 conversions for in_proj (K=1024, KP=1056 incl. LoRA ext)
    cvt16_kernel<<<4096, 256, 0, stream>>>(x,    1024, 256, 1056, A16_in, 4096 * 256);
    cvt16_kernel<<<4096, 256, 0, stream>>>(w_in, 1024, 256, 1056, W16_in, 4096 * 256);
    ext16_kernel<<<512, 256, 0, stream>>>(t16,  1024, 1056, 32, A16_in, 4096);
    ext16_kernel<<<512, 256, 0, stream>>>(lbin, 1024, 1056, 32, W16_in, 4096);
    // 3) in_proj fp16 MFMA GEMM -> xz
    mfma_gemm16<0><<<dim3(32, 32), 256, 0, stream>>>(
        A16_in, W16_in, 1056, xz, 4096, nullptr, 4096, 0);
    // 4) u = silu(conv(xs) + b); also u16 fp16 (delta region)
    conv_silu_kernel<<<(BL * D_INNER) / 256, 256, 0, stream>>>(xz, conv_w, conv_b, u, u16);
    // 5) x_proj fp16 MFMA split-K=8 -> partials -> xdbl
    cvtpad16_kernel<<<(128 * 512 + 255) / 256, 256, 0, stream>>>(w_xp, 96, 512, W16_xp, 128 * 512);
    mfma_gemm16<0><<<dim3(1, 32, SKX), 256, 0, stream>>>(
        u16, W16_xp, 2048, xp_part, 96, nullptr, 96, KCH);
    sk_reduce_kernel<<<(BL * 96 + 255) / 256, 256, 0, stream>>>(xp_part, xdbl, BL * 96);
    // 6) dt_proj fp16 MFMA (K=64) -> delta = softplus(. + b_dt)
    cvt16_kernel<<<(4096 * 16 + 255) / 256, 256, 0, stream>>>(xdbl, 96, 16, 64, A16_dt, 4096 * 16);
    cvt16_kernel<<<(2048 * 16 + 255) / 256, 256, 0, stream>>>(w_dt, 64, 16, 64, W16_dt, 2048 * 16);
    mfma_gemm16<2><<<dim3(16, 32), 256, 0, stream>>>(
        A16_dt, W16_dt, 64, delta, 2048, b_dt, 2048, 0);
    // 7) chunk-parallel selective scan (+ gating); yg aliases delta
    scan_partA<<<NSEG * BATCH * 8, 256, 0, stream>>>(delta, u, xdbl, A_log, hFin, sumd);
    scan_combine<<<(BATCH * D_INNER * 16) / 256, 256, 0, stream>>>(A_log, hFin, sumd);
    scan_partB<<<NSEG * BATCH * 8, 256, 0, stream>>>(delta, u, xdbl, xz, A_log, Dp, hFin, delta);
    // 8) out_proj: t16_out + fp16 conversions (K=2048, KP=2112)
    lora_t_kernel<<<BL, 256, 0, stream>>>(delta, D_INNER, lA_out, D_INNER, t16);
    cvt16_kernel<<<8192, 256, 0, stream>>>(delta, 2048, 512, KP_OUT, A16_out, 4096 * 512);
    cvt16_kernel<<<2048, 256, 0, stream>>>(w_out, 2048, 512, KP_OUT, W16_out, 1024 * 512);
    ext16_kernel<<<(4096 * 64 + 255) / 256, 256, 0, stream>>>(t16,   2048, KP_OUT, 64, A16_out, 4096);
    ext16_kernel<<<(1024 * 64 + 255) / 256, 256, 0, stream>>>(lbout, 2048, KP_OUT, 64, W16_out, 1024);
    // 9) out_proj fp16 split-K=2 -> partials in dead delta region, then reduce
    float* P = delta;   // [2][4096*1024] f32 — y consumed by lora_t + cvt16
    mfma_gemm16<0><<<dim3(8, 32, 2), 256, 0, stream>>>(
        A16_out, W16_out, KP_OUT, P, 1024, nullptr, 1024, KH_OUT);
    sk2_reduce_kernel<<<(4096 * 1024) / 256, 256, 0, stream>>>(P, (float*)d_out, 4096 * 1024);
}

// Round 11
// 410.934 us; speedup vs baseline: 1.7247x; 1.0775x over previous
//
#include <hip/hip_runtime.h>
#include <hip/hip_bf16.h>
#include <hip/hip_fp16.h>
#include <cstdint>
#include <cstddef>

// Problem constants (from reference)
#define D_MODEL 1024
#define D_INNER 2048
#define NSTATE  16
#define DTRANK  64
#define BATCH   2
#define SEQLEN  2048
#define BL      (BATCH*SEQLEN)   // 4096 tokens
#define NSEG    64
#define TSEG    (SEQLEN/NSEG)    // 32
#define SKX     8                // split-K factor for x_proj
#define KCH     (D_INNER/SKX)    // 256
#define LOG2E   1.4426950408889634f
#define HF_BASE ((size_t)NSEG * BATCH * D_INNER * 16)   // 4.19M floats

typedef __attribute__((ext_vector_type(8))) _Float16 f16x8;
typedef __attribute__((ext_vector_type(4))) float f32x4;

__device__ __forceinline__ float softplusf(float x) {
    return fmaxf(x, 0.f) + log1pf(expf(-fabsf(x)));
}
__device__ __forceinline__ unsigned short f2h(float x) {
    __half h = __float2half(x);
    return *(unsigned short*)&h;
}
// hF/sumd live in the dead xs-half of xz (cols 0..2047 of each 4096-row):
// linear index i -> xz offset (i>>11)*4096 + (i&2047). 4-aligned accesses
// never straddle a 2048 block.
__device__ __forceinline__ float* hfp(float* xzb, size_t i) {
    return xzb + (i >> 11) * 4096 + (i & 2047);
}
__device__ __forceinline__ const float* hfpc(const float* xzb, size_t i) {
    return xzb + (i >> 11) * 4096 + (i & 2047);
}
// async global->LDS, 16B per lane (dest must be linear: base + lane*16)
__device__ __forceinline__ void gll16(const void* g, void* l) {
    __builtin_amdgcn_global_load_lds(
        (const __attribute__((address_space(1))) void*)g,
        (__attribute__((address_space(3))) void*)l, 16, 0, 0);
}

// ---- lbp[n,r] = lora_B[n,r] * mask[n] * 2.0 ----
__global__ __launch_bounds__(256) void premul_kernel(
        const float* __restrict__ lb, const float* __restrict__ mask,
        float* __restrict__ out, int total) {
    int i = blockIdx.x * 256 + threadIdx.x;
    if (i < total) out[i] = lb[i] * mask[i >> 4] * 2.0f;
}

// ---- T[m,r] = sum_k X[m,k] * LA[r,k]   (r < 16) ----
__global__ __launch_bounds__(256) void lora_t_kernel(
        const float* __restrict__ X, int ldx,
        const float* __restrict__ LA, int K,
        float* __restrict__ T) {
    int m = blockIdx.x;
    int r = threadIdx.x >> 4;
    int l = threadIdx.x & 15;
    const float* xrow = X + (size_t)m * ldx;
    const float* arow = LA + (size_t)r * K;
    float s = 0.f;
    for (int k = 4 * l; k < K; k += 64) {
        float4 xv = *(const float4*)(xrow + k);
        float4 av = *(const float4*)(arow + k);
        s += xv.x * av.x + xv.y * av.y + xv.z * av.z + xv.w * av.w;
    }
    #pragma unroll
    for (int o = 8; o; o >>= 1) s += __shfl_xor(s, o, 16);
    if (l == 0) T[(size_t)m * 16 + r] = s;
}

// ---- fp16 convert: dst[m][k] = fp16(src[m][k]) ----
__global__ __launch_bounds__(256) void cvt16_kernel(
        const float* __restrict__ src, int lda, int K4, int KP,
        unsigned short* __restrict__ dst, int total4) {
    int idx = blockIdx.x * 256 + threadIdx.x;
    if (idx >= total4) return;
    int m = idx / K4;
    int kq = idx - m * K4;
    float4 v = *(const float4*)(src + (size_t)m * lda + kq * 4);
    ushort4 h;
    h.x = f2h(v.x); h.y = f2h(v.y); h.z = f2h(v.z); h.w = f2h(v.w);
    *(ushort4*)(dst + (size_t)m * KP + kq * 4) = h;
}

// ---- fp16 convert with row padding: rows >= Msrc write zeros ----
__global__ __launch_bounds__(256) void cvtpad16_kernel(
        const float* __restrict__ src, int Msrc, int K4,
        unsigned short* __restrict__ dst, int total4) {
    int idx = blockIdx.x * 256 + threadIdx.x;
    if (idx >= total4) return;
    int m = idx / K4;
    int kq = idx - m * K4;
    ushort4 h = {0, 0, 0, 0};
    if (m < Msrc) {
        float4 v = *(const float4*)(src + (size_t)m * (K4 * 4) + kq * 4);
        h.x = f2h(v.x); h.y = f2h(v.y); h.z = f2h(v.z); h.w = f2h(v.w);
    }
    *(ushort4*)(dst + (size_t)m * (K4 * 4) + kq * 4) = h;
}

// ---- LoRA K-extension columns (fp16): cols [K,K+16)=t16, [K+16,K+ncols)=0 ----
__global__ __launch_bounds__(256) void ext16_kernel(
        const float* __restrict__ t16, int K, int KP, int ncols,
        unsigned short* __restrict__ dst, int M) {
    int idx = blockIdx.x * 256 + threadIdx.x;
    if (idx >= M * ncols) return;
    int c = idx % ncols, m = idx / ncols;
    unsigned short hv = 0;
    if (c < 16) hv = f2h(t16[(size_t)m * 16 + c]);
    dst[(size_t)m * KP + K + c] = hv;
}

// ---- fp16 single-pass MFMA GEMM, 2-phase dbuf, optional split-K + N bound --
template<int EPI>
__global__ __launch_bounds__(256, 4) void mfma_gemm16(
        const unsigned short* __restrict__ Ag, const unsigned short* __restrict__ Wg,
        int KP, float* __restrict__ C, int ldc,
        const float* __restrict__ bias, int Nbound, int kchunk) {
    __shared__ __align__(16) short Ash[2][4][128][8];
    __shared__ __align__(16) short Wsh[2][4][128][8];
    const int tid = threadIdx.x;
    const int bn0 = blockIdx.x * 128, bm0 = blockIdx.y * 128;
    const int wave = tid >> 6, lane = tid & 63;
    const int wr = (wave >> 1) * 64, wc = (wave & 1) * 64;
    const int fr = lane & 15, fg = lane >> 4;
    int koff0 = 0, KT;
    if (kchunk) {
        koff0 = blockIdx.z * kchunk;
        KT = kchunk >> 5;
        C += (size_t)blockIdx.z * gridDim.y * 128 * ldc;
    } else {
        KT = KP >> 5;
    }
    const int srow = tid & 127, skg = tid >> 7;

    const unsigned short* pA = Ag + (size_t)(bm0 + srow) * KP + koff0 + skg * 8;
    const unsigned short* pW = Wg + (size_t)(bn0 + srow) * KP + koff0 + skg * 8;

    f32x4 acc[4][4];
    #pragma unroll
    for (int i = 0; i < 4; ++i)
        #pragma unroll
        for (int j = 0; j < 4; ++j) acc[i][j] = (f32x4){0.f, 0.f, 0.f, 0.f};

    auto stage = [&](int kt, int pb) {
        const int koff = kt * 32;
        gll16(pA + koff,      &Ash[pb][skg    ][srow][0]);
        gll16(pA + koff + 16, &Ash[pb][skg + 2][srow][0]);
        gll16(pW + koff,      &Wsh[pb][skg    ][srow][0]);
        gll16(pW + koff + 16, &Wsh[pb][skg + 2][srow][0]);
    };

    stage(0, 0);
    for (int kt = 0; kt < KT; ++kt) {
        const int cur = kt & 1;
        __syncthreads();   // drains vmcnt(0): buf[cur] staged; prev reads done
        if (kt + 1 < KT) stage(kt + 1, cur ^ 1);
        f16x8 a[4], w[4];
        #pragma unroll
        for (int i = 0; i < 4; ++i) {
            a[i] = *(const f16x8*)&Ash[cur][fg][wr + i * 16 + fr][0];
            w[i] = *(const f16x8*)&Wsh[cur][fg][wc + i * 16 + fr][0];
        }
        #pragma unroll
        for (int i = 0; i < 4; ++i)
            #pragma unroll
            for (int j = 0; j < 4; ++j)
                acc[i][j] = __builtin_amdgcn_mfma_f32_16x16x32_f16(a[i], w[j], acc[i][j], 0, 0, 0);
    }
    // C/D layout: col = lane&15, row = (lane>>4)*4 + q
    #pragma unroll
    for (int i = 0; i < 4; ++i) {
        #pragma unroll
        for (int j = 0; j < 4; ++j) {
            int n = bn0 + wc + j * 16 + fr;
            if (n < Nbound) {
                #pragma unroll
                for (int q = 0; q < 4; ++q) {
                    int m = bm0 + wr + i * 16 + fg * 4 + q;
                    float v = acc[i][j][q];
                    if (EPI == 2) v = softplusf(v + bias[n]);
                    C[(size_t)m * ldc + n] = v;
                }
            }
        }
    }
}

// ---- out[i] = p[i] + p[total+i]  (split-K=2 reduce) ----
__global__ __launch_bounds__(256) void sk2_reduce_kernel(
        const float* __restrict__ p, float* __restrict__ out, int total) {
    int i = blockIdx.x * 256 + threadIdx.x;
    if (i < total) out[i] = p[i] + p[(size_t)total + i];
}

// ---- reduce split-K partials (SKX-way, x_proj) ----
__global__ __launch_bounds__(256) void sk_reduce_kernel(
        const float* __restrict__ part, float* __restrict__ out, int total) {
    int i = blockIdx.x * 256 + threadIdx.x;
    if (i >= total) return;
    float s = 0.f;
    #pragma unroll
    for (int sk = 0; sk < SKX; ++sk) s += part[(size_t)sk * total + i];
    out[i] = s;
}

// ---- depthwise causal conv(4) + bias + SiLU; emits f32 u and fp16 u16 ----
__global__ __launch_bounds__(256) void conv_silu_kernel(
        const float* __restrict__ xz, const float* __restrict__ cw,
        const float* __restrict__ cb, float* __restrict__ u,
        unsigned short* __restrict__ u16) {
    int idx = blockIdx.x * 256 + threadIdx.x;
    int d  = idx & (D_INNER - 1);
    int bl = idx >> 11;
    int l  = bl & (SEQLEN - 1);
    const float* base = xz + (size_t)bl * 4096 + d;
    float4 w = *(const float4*)(cw + d * 4);
    float s = cb[d];
    if (l >= 3) s = fmaf(base[-3 * 4096], w.x, s);
    if (l >= 2) s = fmaf(base[-2 * 4096], w.y, s);
    if (l >= 1) s = fmaf(base[-1 * 4096], w.z, s);
    s = fmaf(base[0], w.w, s);
    float r = s * __builtin_amdgcn_rcpf(1.f + __expf(-s));
    u[idx] = r;
    u16[idx] = f2h(r);
}

// ================= chunk-parallel selective scan (per-thread h[16]) ========
// NSEG=64 segments; 1024 blocks; B/C staged in LDS; hF/sumd in dead xs cols.
__global__ __launch_bounds__(256) void scan_partA(
        const float* __restrict__ delta, const float* __restrict__ u,
        const float* __restrict__ xdbl, const float* __restrict__ A_log,
        float* __restrict__ xzws) {
    __shared__ float Bs[TSEG][16];
    const int tid = threadIdx.x;
    const int bx  = blockIdx.x;
    const int seg = bx >> 4;
    const int b   = (bx >> 3) & 1;
    const int d   = (bx & 7) * 256 + tid;
    const int t0  = seg * TSEG;
    // stage B slab: TSEG*16 = 512 floats
    {
        const float* bc0 = xdbl + ((size_t)b * SEQLEN + t0) * 96 + 64;
        for (int i = tid; i < TSEG * 16; i += 256)
            Bs[i >> 4][i & 15] = bc0[(size_t)(i >> 4) * 96 + (i & 15)];
    }
    float An2[16];
    #pragma unroll
    for (int q = 0; q < 4; ++q) {
        float4 a = *(const float4*)(A_log + d * 16 + q * 4);
        An2[q*4+0] = -__expf(a.x) * LOG2E;
        An2[q*4+1] = -__expf(a.y) * LOG2E;
        An2[q*4+2] = -__expf(a.z) * LOG2E;
        An2[q*4+3] = -__expf(a.w) * LOG2E;
    }
    const float* dl = delta + ((size_t)b * SEQLEN + t0) * D_INNER + d;
    const float* uu = u     + ((size_t)b * SEQLEN + t0) * D_INNER + d;
    float h[16];
    #pragma unroll
    for (int n = 0; n < 16; ++n) h[n] = 0.f;
    float sd = 0.f;
    float pdv[4], puv[4];
    #pragma unroll
    for (int j = 0; j < 4; ++j) {
        pdv[j] = dl[(size_t)j * D_INNER];
        puv[j] = uu[(size_t)j * D_INNER];
    }
    __syncthreads();
    for (int t4 = 0; t4 < TSEG; t4 += 4) {
        #pragma unroll
        for (int j = 0; j < 4; ++j) {
            const float dv = pdv[j], uv = puv[j];
            if (t4 + 4 < TSEG) {
                pdv[j] = dl[(size_t)(t4 + 4 + j) * D_INNER];
                puv[j] = uu[(size_t)(t4 + 4 + j) * D_INNER];
            }
            const float dvuv = dv * uv;
            sd += dv;
            #pragma unroll
            for (int n = 0; n < 16; ++n)
                h[n] = fmaf(exp2f(dv * An2[n]), h[n], dvuv * Bs[t4 + j][n]);
        }
    }
    const size_t o = (size_t)seg * (BATCH * D_INNER) + (size_t)b * D_INNER + d;
    #pragma unroll
    for (int q = 0; q < 4; ++q)
        *(float4*)hfp(xzws, o * 16 + q * 4) =
            make_float4(h[q*4], h[q*4+1], h[q*4+2], h[q*4+3]);
    *hfp(xzws, HF_BASE + o) = sd;
}

// combine over NSEG=64 segments, 4-deep load pipeline (in-place on hF map)
__global__ __launch_bounds__(256) void scan_combine(
        const float* __restrict__ A_log, float* xzws) {
    int idx = blockIdx.x * 256 + threadIdx.x;   // row*16 + n, 65536 total
    int n = idx & 15, row = idx >> 4;
    int d = row & (D_INNER - 1);
    float An = -__expf(A_log[d * 16 + n]);
    float h = 0.f;
    float f[4], sdv[4];
    #pragma unroll
    for (int j = 0; j < 4; ++j) {
        size_t o = (size_t)j * (BATCH * D_INNER) + row;
        f[j]   = *hfpc(xzws, o * 16 + n);
        sdv[j] = *hfpc(xzws, HF_BASE + o);
    }
    for (int s4 = 0; s4 < NSEG; s4 += 4) {
        float nf[4], nsd[4];
        if (s4 + 4 < NSEG) {
            #pragma unroll
            for (int j = 0; j < 4; ++j) {
                size_t o = (size_t)(s4 + 4 + j) * (BATCH * D_INNER) + row;
                nf[j]  = *hfpc(xzws, o * 16 + n);
                nsd[j] = *hfpc(xzws, HF_BASE + o);
            }
        }
        #pragma unroll
        for (int j = 0; j < 4; ++j) {
            size_t o = (size_t)(s4 + j) * (BATCH * D_INNER) + row;
            *hfp(xzws, o * 16 + n) = h;
            h = fmaf(__expf(An * sdv[j]), h, f[j]);
        }
        #pragma unroll
        for (int j = 0; j < 4; ++j) { f[j] = nf[j]; sdv[j] = nsd[j]; }
    }
}

// partB: re-scan from hin (mapped), emit y*silu(z). yg aliases delta.
__global__ __launch_bounds__(256) void scan_partB(
        const float* delta, const float* __restrict__ u,
        const float* __restrict__ xdbl, const float* __restrict__ xz,
        const float* __restrict__ A_log, const float* __restrict__ Dp,
        float* yg) {
    __shared__ float BCs[TSEG][32];
    const int tid = threadIdx.x;
    const int bx  = blockIdx.x;
    const int seg = bx >> 4;
    const int b   = (bx >> 3) & 1;
    const int d   = (bx & 7) * 256 + tid;
    const int t0  = seg * TSEG;
    {
        const float* bc0 = xdbl + ((size_t)b * SEQLEN + t0) * 96 + 64;
        for (int i = tid; i < TSEG * 32; i += 256)
            BCs[i >> 5][i & 31] = bc0[(size_t)(i >> 5) * 96 + (i & 31)];
    }
    float An2[16];
    #pragma unroll
    for (int q = 0; q < 4; ++q) {
        float4 a = *(const float4*)(A_log + d * 16 + q * 4);
        An2[q*4+0] = -__expf(a.x) * LOG2E;
        An2[q*4+1] = -__expf(a.y) * LOG2E;
        An2[q*4+2] = -__expf(a.z) * LOG2E;
        An2[q*4+3] = -__expf(a.w) * LOG2E;
    }
    const float Dd = Dp[d];
    const float* dl = delta + ((size_t)b * SEQLEN + t0) * D_INNER + d;
    const float* uu = u     + ((size_t)b * SEQLEN + t0) * D_INNER + d;
    const float* zz = xz    + ((size_t)b * SEQLEN + t0) * 4096 + D_INNER + d;
    float* yo = yg + ((size_t)b * SEQLEN + t0) * D_INNER + d;
    const size_t o = (size_t)seg * (BATCH * D_INNER) + (size_t)b * D_INNER + d;
    float h[16];
    #pragma unroll
    for (int q = 0; q < 4; ++q) {
        float4 hv = *(const float4*)hfpc(xz, o * 16 + q * 4);
        h[q*4] = hv.x; h[q*4+1] = hv.y; h[q*4+2] = hv.z; h[q*4+3] = hv.w;
    }
    float pdv[4], puv[4], pzv[4];
    #pragma unroll
    for (int j = 0; j < 4; ++j) {
        pdv[j] = dl[(size_t)j * D_INNER];
        puv[j] = uu[(size_t)j * D_INNER];
        pzv[j] = zz[(size_t)j * 4096];
    }
    __syncthreads();
    for (int t4 = 0; t4 < TSEG; t4 += 4) {
        #pragma unroll
        for (int j = 0; j < 4; ++j) {
            const float dv = pdv[j], uv = puv[j], zv = pzv[j];
            if (t4 + 4 < TSEG) {
                pdv[j] = dl[(size_t)(t4 + 4 + j) * D_INNER];
                puv[j] = uu[(size_t)(t4 + 4 + j) * D_INNER];
                pzv[j] = zz[(size_t)(t4 + 4 + j) * 4096];
            }
            const float dvuv = dv * uv;
            #pragma unroll
            for (int n = 0; n < 16; ++n)
                h[n] = fmaf(exp2f(dv * An2[n]), h[n], dvuv * BCs[t4 + j][n]);
            float acc[4] = {0.f, 0.f, 0.f, 0.f};
            #pragma unroll
            for (int n = 0; n < 16; ++n)
                acc[n & 3] = fmaf(h[n], BCs[t4 + j][16 + n], acc[n & 3]);
            float yv = fmaf(uv, Dd, (acc[0] + acc[1]) + (acc[2] + acc[3]));
            float sig = zv * __builtin_amdgcn_rcpf(1.f + __expf(-zv));
            yo[(size_t)(t4 + j) * D_INNER] = yv * sig;
        }
    }
}

extern "C" void kernel_launch(void* const* d_in, const int* in_sizes, int n_in,
                              void* d_out, int out_size, void* d_ws, size_t ws_size,
                              hipStream_t stream) {
    const float* x        = (const float*)d_in[0];
    const float* w_in     = (const float*)d_in[1];
    const float* lA_in    = (const float*)d_in[2];
    const float* lB_in    = (const float*)d_in[3];
    const float* mask_in  = (const float*)d_in[4];
    const float* conv_w   = (const float*)d_in[5];
    const float* conv_b   = (const float*)d_in[6];
    const float* w_xp     = (const float*)d_in[7];
    const float* w_dt     = (const float*)d_in[8];
    const float* b_dt     = (const float*)d_in[9];
    const float* A_log    = (const float*)d_in[10];
    const float* Dp       = (const float*)d_in[11];
    const float* w_out    = (const float*)d_in[12];
    const float* lA_out   = (const float*)d_in[13];
    const float* lB_out   = (const float*)d_in[14];
    const float* mask_out = (const float*)d_in[15];

    // f32 workspace layout
    float* ws    = (float*)d_ws;
    float* xz    = ws;                              // [BL,4096] (xs half also hF/sumd)
    float* u     = xz    + (size_t)BL * 4096;       // [BL,2048]
    float* delta = u     + (size_t)BL * D_INNER;    // [BL,2048] (delta/yg; u16; out partials)
    float* xdbl  = delta + (size_t)BL * D_INNER;    // [BL,96]
    float* t16   = xdbl  + (size_t)BL * 96;         // [BL,16]
    float* lbin  = t16   + (size_t)BL * 16;         // [4096,16]
    float* lbout = lbin  + (size_t)4096 * 16;       // [1024,16]

    // fp16 arenas for in_proj in dead u region
    unsigned short* A16_in = (unsigned short*)u;                 // [4096][1056]
    unsigned short* W16_in = A16_in + (size_t)4096 * 1056;       // [4096][1056]

    // u16 (x_proj A operand) in delta region while delta is dead
    unsigned short* u16 = (unsigned short*)delta;                // [4096][2048]

    // fp16 arenas for out_proj in dead xz region; KP=2112 (2 x 1056)
    const int KP_OUT = 2112, KH_OUT = 1056;
    unsigned short* A16_out = (unsigned short*)xz;               // [4096][2112]
    unsigned short* W16_out = A16_out + (size_t)4096 * KP_OUT;   // [1024][2112]

    // d_out f32 scratch (pre-final uses)
    float* outf    = (float*)d_out;
    float* xp_part = outf;                                   // [SKX][BL*96] = 12.6MB
    unsigned short* W16_xp = (unsigned short*)(outf + (size_t)SKX * BL * 96); // [128][2048]
    unsigned short* A16_dt = (unsigned short*)d_out;             // [4096][64] (after xp consumed)
    unsigned short* W16_dt = A16_dt + (size_t)4096 * 64;         // [2048][64]

    // 1) LoRA premultiply + t16_in
    premul_kernel<<<(4096 * 16 + 255) / 256, 256, 0, stream>>>(lB_in, mask_in, lbin, 4096 * 16);
    premul_kernel<<<(1024 * 16 + 255) / 256, 256, 0, stream>>>(lB_out, mask_out, lbout, 1024 * 16);
    lora_t_kernel<<<BL, 256, 0, stream>>>(x, D_MODEL, lA_in, D_MODEL, t16);
    // 2) fp16 conversions for in_proj (K=1024, KP=1056 incl. LoRA ext)
    cvt16_kernel<<<4096, 256, 0, stream>>>(x,    1024, 256, 1056, A16_in, 4096 * 256);
    cvt16_kernel<<<4096, 256, 0, stream>>>(w_in, 1024, 256, 1056, W16_in, 4096 * 256);
    ext16_kernel<<<512, 256, 0, stream>>>(t16,  1024, 1056, 32, A16_in, 4096);
    ext16_kernel<<<512, 256, 0, stream>>>(lbin, 1024, 1056, 32, W16_in, 4096);
    // 3) in_proj fp16 MFMA GEMM -> xz
    mfma_gemm16<0><<<dim3(32, 32), 256, 0, stream>>>(
        A16_in, W16_in, 1056, xz, 4096, nullptr, 4096, 0);
    // 4) u = silu(conv(xs) + b); also u16 fp16 (delta region)
    conv_silu_kernel<<<(BL * D_INNER) / 256, 256, 0, stream>>>(xz, conv_w, conv_b, u, u16);
    // 5) x_proj fp16 MFMA split-K=8 -> partials -> xdbl
    cvtpad16_kernel<<<(128 * 512 + 255) / 256, 256, 0, stream>>>(w_xp, 96, 512, W16_xp, 128 * 512);
    mfma_gemm16<0><<<dim3(1, 32, SKX), 256, 0, stream>>>(
        u16, W16_xp, 2048, xp_part, 96, nullptr, 96, KCH);
    sk_reduce_kernel<<<(BL * 96 + 255) / 256, 256, 0, stream>>>(xp_part, xdbl, BL * 96);
    // 6) dt_proj fp16 MFMA (K=64) -> delta = softplus(. + b_dt)
    cvt16_kernel<<<(4096 * 16 + 255) / 256, 256, 0, stream>>>(xdbl, 96, 16, 64, A16_dt, 4096 * 16);
    cvt16_kernel<<<(2048 * 16 + 255) / 256, 256, 0, stream>>>(w_dt, 64, 16, 64, W16_dt, 2048 * 16);
    mfma_gemm16<2><<<dim3(16, 32), 256, 0, stream>>>(
        A16_dt, W16_dt, 64, delta, 2048, b_dt, 2048, 0);
    // 7) chunk-parallel selective scan (+ gating); hF/sumd in dead xs of xz
    scan_partA<<<NSEG * BATCH * 8, 256, 0, stream>>>(delta, u, xdbl, A_log, xz);
    scan_combine<<<(BATCH * D_INNER * 16) / 256, 256, 0, stream>>>(A_log, xz);
    scan_partB<<<NSEG * BATCH * 8, 256, 0, stream>>>(delta, u, xdbl, xz, A_log, Dp, delta);
    // 8) out_proj: t16_out + fp16 conversions (K=2048, KP=2112)
    lora_t_kernel<<<BL, 256, 0, stream>>>(delta, D_INNER, lA_out, D_INNER, t16);
    cvt16_kernel<<<8192, 256, 0, stream>>>(delta, 2048, 512, KP_OUT, A16_out, 4096 * 512);
    cvt16_kernel<<<2048, 256, 0, stream>>>(w_out, 2048, 512, KP_OUT, W16_out, 1024 * 512);
    ext16_kernel<<<(4096 * 64 + 255) / 256, 256, 0, stream>>>(t16,   2048, KP_OUT, 64, A16_out, 4096);
    ext16_kernel<<<(1024 * 64 + 255) / 256, 256, 0, stream>>>(lbout, 2048, KP_OUT, 64, W16_out, 1024);
    // 9) out_proj fp16 split-K=2 -> partials in dead delta region, then reduce
    float* P = delta;   // [2][4096*1024] f32 — y consumed by lora_t + cvt16
    mfma_gemm16<0><<<dim3(8, 32, 2), 256, 0, stream>>>(
        A16_out, W16_out, KP_OUT, P, 1024, nullptr, 1024, KH_OUT);
    sk2_reduce_kernel<<<(4096 * 1024) / 256, 256, 0, stream>>>(P, (float*)d_out, 4096 * 1024);
}